// Round 1
// baseline (766.942 us; speedup 1.0000x reference)
//
#include <hip/hip_runtime.h>
#include <math.h>

// Problem constants
#define C_DIM 512
#define NHEAD 8
#define NPNT 4
#define HDIM 64
#define HS 20      // H == W == D == 20
#define NTOK 8000  // H*W*D
#define NB 2
#define BN_TOK 16000  // B * N

__device__ __forceinline__ int imin(int a, int b) { return a < b ? a : b; }

// ---------------------------------------------------------------------------
// Tiled transpose: in (R,S) row-major -> out (S,R) row-major, batched over z.
// ---------------------------------------------------------------------------
__global__ __launch_bounds__(256) void transpose_rs(
    const float* __restrict__ in, float* __restrict__ out, int R, int S)
{
    __shared__ float tile[32][33];
    int b = blockIdx.z;
    const float* inb = in + (size_t)b * R * S;
    float* outb = out + (size_t)b * R * S;
    int s0 = blockIdx.x * 32, r0 = blockIdx.y * 32;
    int tx = threadIdx.x & 31, ty = threadIdx.x >> 5;  // ty: 0..7
#pragma unroll
    for (int i = 0; i < 4; i++) {
        int r = r0 + ty + i * 8, s = s0 + tx;
        if (r < R && s < S) tile[ty + i * 8][tx] = inb[(size_t)r * S + s];
    }
    __syncthreads();
#pragma unroll
    for (int i = 0; i < 4; i++) {
        int s = s0 + ty + i * 8, r = r0 + tx;
        if (r < R && s < S) outb[(size_t)s * R + r] = tile[tx][ty + i * 8];
    }
}

// ---------------------------------------------------------------------------
// LayerNorm over C with implicit (B,C,N)->(B,N,C) transpose.
// One block (256 threads) per token; thread t handles channels t and t+256.
// ---------------------------------------------------------------------------
__global__ __launch_bounds__(256) void ln_transpose_kernel(
    const float* __restrict__ fq, const float* __restrict__ gamma,
    const float* __restrict__ beta, float* __restrict__ q)
{
    int bn = blockIdx.x;
    int b = bn / NTOK, n = bn - b * NTOK;
    const float* src = fq + (size_t)b * C_DIM * NTOK + n;
    int tid = threadIdx.x;
    float x0 = src[(size_t)tid * NTOK];
    float x1 = src[(size_t)(tid + 256) * NTOK];
    float s = x0 + x1, ss = x0 * x0 + x1 * x1;
#pragma unroll
    for (int o = 32; o > 0; o >>= 1) {
        s += __shfl_down(s, o);
        ss += __shfl_down(ss, o);
    }
    __shared__ float sS[4], sQ[4];
    int wid = tid >> 6, lane = tid & 63;
    if (lane == 0) { sS[wid] = s; sQ[wid] = ss; }
    __syncthreads();
    float S = sS[0] + sS[1] + sS[2] + sS[3];
    float SQ = sQ[0] + sQ[1] + sQ[2] + sQ[3];
    float mu = S * (1.0f / 512.0f);
    float var = SQ * (1.0f / 512.0f) - mu * mu;
    float rs = rsqrtf(var + 1e-5f);
    float* dst = q + (size_t)bn * C_DIM;
    dst[tid]       = (x0 - mu) * rs * gamma[tid]       + beta[tid];
    dst[tid + 256] = (x1 - mu) * rs * gamma[tid + 256] + beta[tid + 256];
}

// ---------------------------------------------------------------------------
// fp32 GEMM, K fixed at 512: C[M,Nout] = A[M,512] @ W[512,Nout] + bias,
// optional relu. 64x64 tile, BK=16, 256 threads, 4x4 per thread.
// ---------------------------------------------------------------------------
__global__ __launch_bounds__(256) void gemm_k512(
    const float* __restrict__ A, const float* __restrict__ Wm,
    const float* __restrict__ bias, float* __restrict__ Cout,
    int M, int Nout, int relu)
{
    __shared__ float As[16][68];  // [k][m], +4 pad keeps 16B alignment per row
    __shared__ float Bs[16][64];  // [k][n]
    int tid = threadIdx.x;
    int bm = blockIdx.y * 64, bn = blockIdx.x * 64;
    int tx = tid & 15, ty = tid >> 4;
    float acc[4][4] = {};
    int ar = tid >> 2;        // 0..63 : A tile row
    int ac = (tid & 3) << 2;  // 0,4,8,12 : A tile k-offset
    int br = tid >> 4;        // 0..15 : B tile k-row
    int bc = (tid & 15) << 2; // 0..60 : B tile col

    for (int k0 = 0; k0 < 512; k0 += 16) {
        int arow = bm + ar;
        float4 av = make_float4(0.f, 0.f, 0.f, 0.f);
        if (arow < M)
            av = *reinterpret_cast<const float4*>(A + (size_t)arow * 512 + k0 + ac);
        int col = bn + bc;
        float4 bv;
        if (col + 3 < Nout) {
            bv = *reinterpret_cast<const float4*>(Wm + (size_t)(k0 + br) * Nout + col);
        } else {
            bv.x = (col + 0 < Nout) ? Wm[(size_t)(k0 + br) * Nout + col + 0] : 0.f;
            bv.y = (col + 1 < Nout) ? Wm[(size_t)(k0 + br) * Nout + col + 1] : 0.f;
            bv.z = (col + 2 < Nout) ? Wm[(size_t)(k0 + br) * Nout + col + 2] : 0.f;
            bv.w = (col + 3 < Nout) ? Wm[(size_t)(k0 + br) * Nout + col + 3] : 0.f;
        }
        __syncthreads();  // previous iteration's compute done before overwrite
        As[ac + 0][ar] = av.x;
        As[ac + 1][ar] = av.y;
        As[ac + 2][ar] = av.z;
        As[ac + 3][ar] = av.w;
        *reinterpret_cast<float4*>(&Bs[br][bc]) = bv;
        __syncthreads();
#pragma unroll
        for (int kk = 0; kk < 16; ++kk) {
            float a0 = As[kk][ty * 4 + 0], a1 = As[kk][ty * 4 + 1];
            float a2 = As[kk][ty * 4 + 2], a3 = As[kk][ty * 4 + 3];
            float b0 = Bs[kk][tx * 4 + 0], b1 = Bs[kk][tx * 4 + 1];
            float b2 = Bs[kk][tx * 4 + 2], b3 = Bs[kk][tx * 4 + 3];
            acc[0][0] += a0 * b0; acc[0][1] += a0 * b1; acc[0][2] += a0 * b2; acc[0][3] += a0 * b3;
            acc[1][0] += a1 * b0; acc[1][1] += a1 * b1; acc[1][2] += a1 * b2; acc[1][3] += a1 * b3;
            acc[2][0] += a2 * b0; acc[2][1] += a2 * b1; acc[2][2] += a2 * b2; acc[2][3] += a2 * b3;
            acc[3][0] += a3 * b0; acc[3][1] += a3 * b1; acc[3][2] += a3 * b2; acc[3][3] += a3 * b3;
        }
    }
#pragma unroll
    for (int i = 0; i < 4; i++) {
        int row = bm + ty * 4 + i;
        if (row >= M) continue;
#pragma unroll
        for (int j = 0; j < 4; j++) {
            int col = bn + tx * 4 + j;
            if (col < Nout) {
                float v = acc[i][j] + bias[col];
                if (relu) v = fmaxf(v, 0.f);
                Cout[(size_t)row * Nout + col] = v;
            }
        }
    }
}

// ---------------------------------------------------------------------------
// Fused softmax(attn logits) + offset clip + trilinear sample + einsum.
// One wave per (b,n,h); lane = head-channel. vol is channels-last (B,N,C).
// Reference quirk: off-ch0 drives the x(W) axis, ch1 the y(H) axis, ch2 z(D);
// with H=W=D the normalization collapses to clip(base+off, 0, 19).
// ---------------------------------------------------------------------------
__global__ __launch_bounds__(256) void sample_kernel(
    const float* __restrict__ vol, const float* __restrict__ offb,
    const float* __restrict__ lgb, float* __restrict__ outp)
{
    int wid = threadIdx.x >> 6, lane = threadIdx.x & 63;
    int g = blockIdx.x * 4 + wid;  // 0 .. BN_TOK*NHEAD-1
    int bn = g >> 3, h = g & 7;
    int b = bn / NTOK, n = bn - b * NTOK;
    int y = n / 400;
    int r2 = n - y * 400;
    int x = r2 / 20;
    int z = r2 - x * 20;

    const float* op = offb + (size_t)bn * 96 + h * 12;
    const float* lp = lgb + (size_t)bn * 32 + h * 4;
    float l0 = lp[0], l1 = lp[1], l2 = lp[2], l3 = lp[3];
    float mx = fmaxf(fmaxf(l0, l1), fmaxf(l2, l3));
    float e0 = expf(l0 - mx), e1 = expf(l1 - mx), e2 = expf(l2 - mx), e3 = expf(l3 - mx);
    float inv = 1.f / (e0 + e1 + e2 + e3);
    float at[4] = {e0 * inv, e1 * inv, e2 * inv, e3 * inv};

    const float* volb = vol + (size_t)b * NTOK * C_DIM + h * HDIM + lane;
    float accv = 0.f;
#pragma unroll
    for (int p = 0; p < 4; p++) {
        float o0 = fminf(fmaxf(op[p * 3 + 0], -3.f), 3.f);
        float o1 = fminf(fmaxf(op[p * 3 + 1], -3.f), 3.f);
        float o2 = fminf(fmaxf(op[p * 3 + 2], -3.f), 3.f);
        float ix = fminf(fmaxf((float)y + o0, 0.f), 19.f);  // W axis
        float iy = fminf(fmaxf((float)x + o1, 0.f), 19.f);  // H axis
        float iz = fminf(fmaxf((float)z + o2, 0.f), 19.f);  // D axis
        float xf = floorf(ix), yf = floorf(iy), zf = floorf(iz);
        float fx = ix - xf, fy = iy - yf, fz = iz - zf;
        int x0 = (int)xf, y0 = (int)yf, z0 = (int)zf;
        int x1 = imin(x0 + 1, 19), y1 = imin(y0 + 1, 19), z1 = imin(z0 + 1, 19);
        // spatial = yi*400 + xi*20 + zi, channels contiguous
        float v000 = volb[(size_t)(y0 * 400 + x0 * 20 + z0) * C_DIM];
        float v001 = volb[(size_t)(y0 * 400 + x1 * 20 + z0) * C_DIM];
        float v010 = volb[(size_t)(y1 * 400 + x0 * 20 + z0) * C_DIM];
        float v011 = volb[(size_t)(y1 * 400 + x1 * 20 + z0) * C_DIM];
        float v100 = volb[(size_t)(y0 * 400 + x0 * 20 + z1) * C_DIM];
        float v101 = volb[(size_t)(y0 * 400 + x1 * 20 + z1) * C_DIM];
        float v110 = volb[(size_t)(y1 * 400 + x0 * 20 + z1) * C_DIM];
        float v111 = volb[(size_t)(y1 * 400 + x1 * 20 + z1) * C_DIM];
        float gx0 = 1.f - fx, gy0 = 1.f - fy, gz0 = 1.f - fz;
        float sv = v000 * gz0 * gy0 * gx0 + v001 * gz0 * gy0 * fx
                 + v010 * gz0 * fy * gx0 + v011 * gz0 * fy * fx
                 + v100 * fz * gy0 * gx0 + v101 * fz * gy0 * fx
                 + v110 * fz * fy * gx0 + v111 * fz * fy * fx;
        accv += at[p] * sv;
    }
    outp[(size_t)bn * C_DIM + h * HDIM + lane] = accv;
}

// ---------------------------------------------------------------------------
// Launch
// ---------------------------------------------------------------------------
extern "C" void kernel_launch(void* const* d_in, const int* in_sizes, int n_in,
                              void* d_out, int out_size, void* d_ws, size_t ws_size,
                              hipStream_t stream)
{
    const float* f_query = (const float*)d_in[0];
    const float* f_kv    = (const float*)d_in[1];
    const float* ln_g    = (const float*)d_in[2];
    const float* ln_b    = (const float*)d_in[3];
    const float* Wq      = (const float*)d_in[4];
    const float* bq      = (const float*)d_in[5];
    const float* Wo1     = (const float*)d_in[6];
    const float* bo1     = (const float*)d_in[7];
    const float* Wo2     = (const float*)d_in[8];
    const float* bo2     = (const float*)d_in[9];
    const float* Wa      = (const float*)d_in[10];
    const float* ba      = (const float*)d_in[11];
    const float* Wout    = (const float*)d_in[12];
    const float* bout    = (const float*)d_in[13];
    float* out = (float*)d_out;

    float* ws = (float*)d_ws;
    const size_t SZ = (size_t)BN_TOK * C_DIM;  // 8,192,000 floats
    float* qbuf = ws;            // q, then hidden, then sampled-out
    float* Qb   = ws + SZ;       // Q, then (free)
    float* kvT  = ws + 2 * SZ;   // f_kv channels-last, then out_bnc
    float* offb = ws + 3 * SZ;                          // (BN,96)
    float* lgb  = ws + 3 * SZ + (size_t)BN_TOK * 96;    // (BN,32)
    // total ws: 26,624,000 floats = ~101.6 MiB

    dim3 blk(256);
    // 1. f_kv (B,C,N) -> kvT (B,N,C)
    transpose_rs<<<dim3(250, 16, 2), blk, 0, stream>>>(f_kv, kvT, 512, 8000);
    // 2. q = LN(transpose(f_query))
    ln_transpose_kernel<<<dim3(BN_TOK), blk, 0, stream>>>(f_query, ln_g, ln_b, qbuf);
    // 3. Q = q @ Wq + bq
    gemm_k512<<<dim3(8, 250), blk, 0, stream>>>(qbuf, Wq, bq, Qb, BN_TOK, 512, 0);
    // 4. hidden = relu(Q @ Wo1 + bo1)   (overwrites q)
    gemm_k512<<<dim3(8, 250), blk, 0, stream>>>(Qb, Wo1, bo1, qbuf, BN_TOK, 512, 1);
    // 5. off = hidden @ Wo2 + bo2       (clip fused into sampler)
    gemm_k512<<<dim3(2, 250), blk, 0, stream>>>(qbuf, Wo2, bo2, offb, BN_TOK, 96, 0);
    // 6. logits = Q @ Wa + ba           (softmax fused into sampler)
    gemm_k512<<<dim3(1, 250), blk, 0, stream>>>(Qb, Wa, ba, lgb, BN_TOK, 32, 0);
    // 7. sampled-einsum -> qbuf (hidden dead)
    sample_kernel<<<dim3(BN_TOK * NHEAD / 4), blk, 0, stream>>>(kvT, offb, lgb, qbuf);
    // 8. out_bnc = sampled @ Wout + bout -> kvT (dead after sampling)
    gemm_k512<<<dim3(8, 250), blk, 0, stream>>>(qbuf, Wout, bout, kvT, BN_TOK, 512, 0);
    // 9. (B,N,C) -> (B,C,N) into d_out
    transpose_rs<<<dim3(16, 250, 2), blk, 0, stream>>>(kvT, out, 8000, 512);
}

// Round 2
// 383.381 us; speedup vs baseline: 2.0005x; 2.0005x over previous
//
#include <hip/hip_runtime.h>
#include <math.h>

// Problem constants
#define C_DIM 512
#define NHEAD 8
#define HDIM 64
#define NTOK 8000
#define BN_TOK 16000

typedef __attribute__((ext_vector_type(8))) short bf16x8;
typedef __attribute__((ext_vector_type(4))) float f32x4;
typedef unsigned short u16;

__device__ __forceinline__ int imin(int a, int b) { return a < b ? a : b; }

// fp32 -> bf16 round-to-nearest-even
__device__ __forceinline__ u16 f2bf(float x) {
    union { float f; unsigned u; } c; c.f = x;
    unsigned r = c.u + 0x7FFFu + ((c.u >> 16) & 1u);
    return (u16)(r >> 16);
}

// async global->LDS, 16 bytes per lane (global_load_lds_dwordx4)
__device__ __forceinline__ void async16(const void* g, void* l) {
    __builtin_amdgcn_global_load_lds(
        (const __attribute__((address_space(1))) void*)g,
        (__attribute__((address_space(3))) void*)l, 16, 0, 0);
}

// ---------------------------------------------------------------------------
// Tiled fp32 transpose: in (R,S) -> out (S,R), batched over z.
// ---------------------------------------------------------------------------
__global__ __launch_bounds__(256) void transpose_rs(
    const float* __restrict__ in, float* __restrict__ out, int R, int S)
{
    __shared__ float tile[32][33];
    int b = blockIdx.z;
    const float* inb = in + (size_t)b * R * S;
    float* outb = out + (size_t)b * R * S;
    int s0 = blockIdx.x * 32, r0 = blockIdx.y * 32;
    int tx = threadIdx.x & 31, ty = threadIdx.x >> 5;
#pragma unroll
    for (int i = 0; i < 4; i++) {
        int r = r0 + ty + i * 8, s = s0 + tx;
        if (r < R && s < S) tile[ty + i * 8][tx] = inb[(size_t)r * S + s];
    }
    __syncthreads();
#pragma unroll
    for (int i = 0; i < 4; i++) {
        int s = s0 + ty + i * 8, r = r0 + tx;
        if (r < R && s < S) outb[(size_t)s * R + r] = tile[tx][ty + i * 8];
    }
}

// ---------------------------------------------------------------------------
// Weight convert: W (512 x Nout) fp32 -> Wt (Npad x 512) bf16, pad rows zero.
// grid: (Npad/32, 512/32)
// ---------------------------------------------------------------------------
__global__ __launch_bounds__(256) void wcvt(
    const float* __restrict__ W, u16* __restrict__ Wt, int Nout)
{
    __shared__ float t[32][33];
    int n0 = blockIdx.x * 32, k0 = blockIdx.y * 32;
    int tx = threadIdx.x & 31, ty = threadIdx.x >> 5;
#pragma unroll
    for (int i = 0; i < 4; i++) {
        int k = k0 + ty + i * 8, n = n0 + tx;
        t[ty + i * 8][tx] = (n < Nout) ? W[(size_t)k * Nout + n] : 0.f;
    }
    __syncthreads();
#pragma unroll
    for (int i = 0; i < 4; i++) {
        int n = n0 + ty + i * 8, k = k0 + tx;
        Wt[(size_t)n * 512 + k] = f2bf(t[tx][ty + i * 8]);
    }
}

// ---------------------------------------------------------------------------
// LayerNorm over C with implicit (B,C,N)->(B,N,C) transpose; bf16 output.
// ---------------------------------------------------------------------------
__global__ __launch_bounds__(256) void ln_transpose_kernel(
    const float* __restrict__ fq, const float* __restrict__ gamma,
    const float* __restrict__ beta, u16* __restrict__ q)
{
    int bn = blockIdx.x;
    int b = bn / NTOK, n = bn - b * NTOK;
    const float* src = fq + (size_t)b * C_DIM * NTOK + n;
    int tid = threadIdx.x;
    float x0 = src[(size_t)tid * NTOK];
    float x1 = src[(size_t)(tid + 256) * NTOK];
    float s = x0 + x1, ss = x0 * x0 + x1 * x1;
#pragma unroll
    for (int o = 32; o > 0; o >>= 1) {
        s += __shfl_down(s, o);
        ss += __shfl_down(ss, o);
    }
    __shared__ float sS[4], sQ[4];
    int wid = tid >> 6, lane = tid & 63;
    if (lane == 0) { sS[wid] = s; sQ[wid] = ss; }
    __syncthreads();
    float S = sS[0] + sS[1] + sS[2] + sS[3];
    float SQ = sQ[0] + sQ[1] + sQ[2] + sQ[3];
    float mu = S * (1.0f / 512.0f);
    float var = SQ * (1.0f / 512.0f) - mu * mu;
    float rs = rsqrtf(var + 1e-5f);
    u16* dst = q + (size_t)bn * C_DIM;
    dst[tid]       = f2bf((x0 - mu) * rs * gamma[tid]       + beta[tid]);
    dst[tid + 256] = f2bf((x1 - mu) * rs * gamma[tid + 256] + beta[tid + 256]);
}

// ---------------------------------------------------------------------------
// bf16 MFMA GEMM (m97 structure): C[M,Nout] = A[M,512] @ Bt[N,512]^T + bias.
// A row-major bf16, Bt row-major bf16 (transposed weight, rows padded to 128).
// 128x128 tile, BK=32, 256 thr = 4 waves, each wave 64x64 via 16 MFMAs/iter.
// XOR-swizzled LDS: staged global k-segment (seg^((row>>1)&3)) lands at slot
// seg -> fragment ds_read_b128 is 2-way bank aliased (free, m136).
// Output fp32 (Cb==null) or bf16. M must be a multiple of 128.
// ---------------------------------------------------------------------------
__global__ __launch_bounds__(256) void gemm_bf16(
    const u16* __restrict__ A, const u16* __restrict__ Bt,
    const float* __restrict__ bias, float* __restrict__ Cf,
    u16* __restrict__ Cb, int Nout, int ldc, int relu)
{
    __shared__ u16 As[128 * 32];  // [row][kseg] 8 KB
    __shared__ u16 Bs[128 * 32];
    int tid = threadIdx.x, lane = tid & 63, wv = tid >> 6;
    int bm = blockIdx.y * 128, bn = blockIdx.x * 128;
    int wm = (wv >> 1) * 64, wn = (wv & 1) * 64;

    f32x4 acc[4][4];
#pragma unroll
    for (int i = 0; i < 4; i++)
#pragma unroll
        for (int j = 0; j < 4; j++) acc[i][j] = (f32x4){0.f, 0.f, 0.f, 0.f};

    // staging coordinates (tile-local), 2 chunks of A + 2 of B per thread
    int ci0 = wv * 2, ci1 = wv * 2 + 1;
    int lin0 = ci0 * 64 + lane, lin1 = ci1 * 64 + lane;
    int rA0 = lin0 >> 2, sA0 = (lin0 & 3) ^ ((rA0 >> 1) & 3);
    int rA1 = lin1 >> 2, sA1 = (lin1 & 3) ^ ((rA1 >> 1) & 3);

    const u16* Ab = A + (size_t)bm * 512;
    const u16* Bb = Bt + (size_t)bn * 512;

    int ml = lane & 15, quad = lane >> 4;
    // fragment LDS offsets (in u16 units); swizzle depends only on (row>>1)&3
    int offA[4], offB[4];
#pragma unroll
    for (int i = 0; i < 4; i++) {
        int r = wm + i * 16 + ml;
        offA[i] = r * 32 + (quad ^ ((r >> 1) & 3)) * 8;
        int rb = wn + i * 16 + ml;
        offB[i] = rb * 32 + (quad ^ ((rb >> 1) & 3)) * 8;
    }

    for (int k0 = 0; k0 < 512; k0 += 32) {
        async16(Ab + (size_t)rA0 * 512 + k0 + sA0 * 8, As + ci0 * 512);
        async16(Ab + (size_t)rA1 * 512 + k0 + sA1 * 8, As + ci1 * 512);
        async16(Bb + (size_t)rA0 * 512 + k0 + sA0 * 8, Bs + ci0 * 512);
        async16(Bb + (size_t)rA1 * 512 + k0 + sA1 * 8, Bs + ci1 * 512);
        __syncthreads();  // drains vmcnt (compiler emits waitcnt before barrier)

        bf16x8 af[4], bfr[4];
#pragma unroll
        for (int i = 0; i < 4; i++) {
            af[i]  = *reinterpret_cast<const bf16x8*>(As + offA[i]);
            bfr[i] = *reinterpret_cast<const bf16x8*>(Bs + offB[i]);
        }
#pragma unroll
        for (int i = 0; i < 4; i++)
#pragma unroll
            for (int j = 0; j < 4; j++)
                acc[i][j] = __builtin_amdgcn_mfma_f32_16x16x32_bf16(
                    af[i], bfr[j], acc[i][j], 0, 0, 0);
        __syncthreads();  // protect LDS before next stage
    }

    // epilogue: C/D layout col=lane&15, row=quad*4+reg (m89/m91 verified)
#pragma unroll
    for (int i = 0; i < 4; i++) {
        int row = bm + wm + i * 16 + quad * 4;
#pragma unroll
        for (int j = 0; j < 4; j++) {
            int col = bn + wn + j * 16 + ml;
            if (col < Nout) {
                float bia = bias[col];
#pragma unroll
                for (int rg = 0; rg < 4; rg++) {
                    float v = acc[i][j][rg] + bia;
                    if (relu) v = fmaxf(v, 0.f);
                    size_t idx = (size_t)(row + rg) * ldc + col;
                    if (Cb) Cb[idx] = f2bf(v);
                    else    Cf[idx] = v;
                }
            }
        }
    }
}

// ---------------------------------------------------------------------------
// Fused softmax + offset clip + trilinear sample + einsum. One wave per
// (b,n,h); lane = head-channel. vol channels-last fp32; output bf16.
// Reference quirk: off-ch0 -> W(x) axis, ch1 -> H(y), ch2 -> D(z); H=W=D=20
// collapses normalization to clip(base+off, 0, 19).
// ---------------------------------------------------------------------------
__global__ __launch_bounds__(256) void sample_kernel(
    const float* __restrict__ vol, const float* __restrict__ offb,
    const float* __restrict__ lgb, u16* __restrict__ outp)
{
    int wid = threadIdx.x >> 6, lane = threadIdx.x & 63;
    int g = blockIdx.x * 4 + wid;
    int bn = g >> 3, h = g & 7;
    int b = bn / NTOK, n = bn - b * NTOK;
    int y = n / 400;
    int r2 = n - y * 400;
    int x = r2 / 20;
    int z = r2 - x * 20;

    const float* op = offb + (size_t)bn * 96 + h * 12;
    const float* lp = lgb + (size_t)bn * 32 + h * 4;
    float l0 = lp[0], l1 = lp[1], l2 = lp[2], l3 = lp[3];
    float mx = fmaxf(fmaxf(l0, l1), fmaxf(l2, l3));
    float e0 = expf(l0 - mx), e1 = expf(l1 - mx), e2 = expf(l2 - mx), e3 = expf(l3 - mx);
    float inv = 1.f / (e0 + e1 + e2 + e3);
    float at[4] = {e0 * inv, e1 * inv, e2 * inv, e3 * inv};

    const float* volb = vol + (size_t)b * NTOK * C_DIM + h * HDIM + lane;
    float accv = 0.f;
#pragma unroll
    for (int p = 0; p < 4; p++) {
        float o0 = fminf(fmaxf(op[p * 3 + 0], -3.f), 3.f);
        float o1 = fminf(fmaxf(op[p * 3 + 1], -3.f), 3.f);
        float o2 = fminf(fmaxf(op[p * 3 + 2], -3.f), 3.f);
        float ix = fminf(fmaxf((float)y + o0, 0.f), 19.f);
        float iy = fminf(fmaxf((float)x + o1, 0.f), 19.f);
        float iz = fminf(fmaxf((float)z + o2, 0.f), 19.f);
        float xf = floorf(ix), yf = floorf(iy), zf = floorf(iz);
        float fx = ix - xf, fy = iy - yf, fz = iz - zf;
        int x0 = (int)xf, y0 = (int)yf, z0 = (int)zf;
        int x1 = imin(x0 + 1, 19), y1 = imin(y0 + 1, 19), z1 = imin(z0 + 1, 19);
        float v000 = volb[(size_t)(y0 * 400 + x0 * 20 + z0) * C_DIM];
        float v001 = volb[(size_t)(y0 * 400 + x1 * 20 + z0) * C_DIM];
        float v010 = volb[(size_t)(y1 * 400 + x0 * 20 + z0) * C_DIM];
        float v011 = volb[(size_t)(y1 * 400 + x1 * 20 + z0) * C_DIM];
        float v100 = volb[(size_t)(y0 * 400 + x0 * 20 + z1) * C_DIM];
        float v101 = volb[(size_t)(y0 * 400 + x1 * 20 + z1) * C_DIM];
        float v110 = volb[(size_t)(y1 * 400 + x0 * 20 + z1) * C_DIM];
        float v111 = volb[(size_t)(y1 * 400 + x1 * 20 + z1) * C_DIM];
        float gx0 = 1.f - fx, gy0 = 1.f - fy, gz0 = 1.f - fz;
        float sv = v000 * gz0 * gy0 * gx0 + v001 * gz0 * gy0 * fx
                 + v010 * gz0 * fy * gx0 + v011 * gz0 * fy * fx
                 + v100 * fz * gy0 * gx0 + v101 * fz * gy0 * fx
                 + v110 * fz * fy * gx0 + v111 * fz * fy * fx;
        accv += at[p] * sv;
    }
    outp[(size_t)bn * C_DIM + h * HDIM + lane] = f2bf(accv);
}

// ---------------------------------------------------------------------------
// Launch
// ---------------------------------------------------------------------------
extern "C" void kernel_launch(void* const* d_in, const int* in_sizes, int n_in,
                              void* d_out, int out_size, void* d_ws, size_t ws_size,
                              hipStream_t stream)
{
    const float* f_query = (const float*)d_in[0];
    const float* f_kv    = (const float*)d_in[1];
    const float* ln_g    = (const float*)d_in[2];
    const float* ln_b    = (const float*)d_in[3];
    const float* Wq      = (const float*)d_in[4];
    const float* bq      = (const float*)d_in[5];
    const float* Wo1     = (const float*)d_in[6];
    const float* bo1     = (const float*)d_in[7];
    const float* Wo2     = (const float*)d_in[8];
    const float* bo2     = (const float*)d_in[9];
    const float* Wa      = (const float*)d_in[10];
    const float* ba      = (const float*)d_in[11];
    const float* Wout    = (const float*)d_in[12];
    const float* bout    = (const float*)d_in[13];
    float* out = (float*)d_out;

    float* ws = (float*)d_ws;
    float* kvT  = ws;                 // 8,192,000 f (kv channels-last; later out_bnc)
    float* offb = ws + 8192000;       // 1,536,000 f
    float* lgb  = ws + 9728000;       //   512,000 f
    u16* bws   = (u16*)(ws + 10240000);
    u16* qb    = bws;                 // 8,192,000 bf16 (q; later sampled)
    u16* Qb    = bws + 8192000;       // 8,192,000 bf16
    u16* hid   = bws + 16384000;      // 8,192,000 bf16
    u16* WqT   = bws + 24576000;      // 512x512
    u16* Wo1T  = WqT + 262144;        // 512x512
    u16* WoutT = Wo1T + 262144;       // 512x512
    u16* Wo2T  = WoutT + 262144;      // 128x512 (96 valid, pad 0)
    u16* WaT   = Wo2T + 65536;        // 128x512 (32 valid, pad 0)
    // total ~87.7 MiB

    dim3 blk(256);
    // weight transpose-converts (fp32 [512,N] -> bf16 [Npad,512])
    wcvt<<<dim3(16, 16), blk, 0, stream>>>(Wq,   WqT,   512);
    wcvt<<<dim3(16, 16), blk, 0, stream>>>(Wo1,  Wo1T,  512);
    wcvt<<<dim3(16, 16), blk, 0, stream>>>(Wout, WoutT, 512);
    wcvt<<<dim3(4, 16),  blk, 0, stream>>>(Wo2,  Wo2T,  96);
    wcvt<<<dim3(4, 16),  blk, 0, stream>>>(Wa,   WaT,   32);
    // f_kv (B,C,N) -> kvT (B,N,C) fp32
    transpose_rs<<<dim3(250, 16, 2), blk, 0, stream>>>(f_kv, kvT, 512, 8000);
    // q = LN(transpose(f_query)) -> bf16
    ln_transpose_kernel<<<dim3(BN_TOK), blk, 0, stream>>>(f_query, ln_g, ln_b, qb);
    // Q = q @ Wq + bq -> bf16
    gemm_bf16<<<dim3(4, 125), blk, 0, stream>>>(qb, WqT, bq, nullptr, Qb, 512, 512, 0);
    // hidden = relu(Q @ Wo1 + bo1) -> bf16
    gemm_bf16<<<dim3(4, 125), blk, 0, stream>>>(Qb, Wo1T, bo1, nullptr, hid, 512, 512, 1);
    // off = hidden @ Wo2 + bo2 -> fp32 (clip fused in sampler)
    gemm_bf16<<<dim3(1, 125), blk, 0, stream>>>(hid, Wo2T, bo2, offb, nullptr, 96, 96, 0);
    // logits = Q @ Wa + ba -> fp32 (softmax fused in sampler)
    gemm_bf16<<<dim3(1, 125), blk, 0, stream>>>(Qb, WaT, ba, lgb, nullptr, 32, 32, 0);
    // sampled einsum -> qb (bf16; q dead)
    sample_kernel<<<dim3(BN_TOK * NHEAD / 4), blk, 0, stream>>>(kvT, offb, lgb, qb);
    // out_bnc = sampled @ Wout + bout -> fp32 into kvT (dead)
    gemm_bf16<<<dim3(4, 125), blk, 0, stream>>>(qb, WoutT, bout, kvT, nullptr, 512, 512, 0);
    // (B,N,C) -> (B,C,N)
    transpose_rs<<<dim3(16, 250, 2), blk, 0, stream>>>(kvT, out, 8000, 512);
}

// Round 3
// 353.478 us; speedup vs baseline: 2.1697x; 1.0846x over previous
//
#include <hip/hip_runtime.h>
#include <math.h>

// Problem constants
#define C_DIM 512
#define NHEAD 8
#define HDIM 64
#define NTOK 8000
#define BN_TOK 16000

typedef __attribute__((ext_vector_type(8))) short bf16x8;
typedef __attribute__((ext_vector_type(4))) float f32x4;
typedef unsigned short u16;

__device__ __forceinline__ int imin(int a, int b) { return a < b ? a : b; }

// fp32 -> bf16 round-to-nearest-even
__device__ __forceinline__ u16 f2bf(float x) {
    union { float f; unsigned u; } c; c.f = x;
    unsigned r = c.u + 0x7FFFu + ((c.u >> 16) & 1u);
    return (u16)(r >> 16);
}

// async global->LDS, 16 bytes per lane (global_load_lds_dwordx4)
__device__ __forceinline__ void async16(const void* g, void* l) {
    __builtin_amdgcn_global_load_lds(
        (const __attribute__((address_space(1))) void*)g,
        (__attribute__((address_space(3))) void*)l, 16, 0, 0);
}

__device__ __forceinline__ void fma4(float4& a, const float4& v, float w) {
    a.x = fmaf(v.x, w, a.x);
    a.y = fmaf(v.y, w, a.y);
    a.z = fmaf(v.z, w, a.z);
    a.w = fmaf(v.w, w, a.w);
}

// ---------------------------------------------------------------------------
// Tiled fp32 transpose: in (R,S) -> out (S,R), batched over z.
// ---------------------------------------------------------------------------
__global__ __launch_bounds__(256) void transpose_rs(
    const float* __restrict__ in, float* __restrict__ out, int R, int S)
{
    __shared__ float tile[32][33];
    int b = blockIdx.z;
    const float* inb = in + (size_t)b * R * S;
    float* outb = out + (size_t)b * R * S;
    int s0 = blockIdx.x * 32, r0 = blockIdx.y * 32;
    int tx = threadIdx.x & 31, ty = threadIdx.x >> 5;
#pragma unroll
    for (int i = 0; i < 4; i++) {
        int r = r0 + ty + i * 8, s = s0 + tx;
        if (r < R && s < S) tile[ty + i * 8][tx] = inb[(size_t)r * S + s];
    }
    __syncthreads();
#pragma unroll
    for (int i = 0; i < 4; i++) {
        int s = s0 + ty + i * 8, r = r0 + tx;
        if (r < R && s < S) outb[(size_t)s * R + r] = tile[tx][ty + i * 8];
    }
}

// ---------------------------------------------------------------------------
// Weight convert: W (512 x Nout) fp32 -> Wt (Npad x 512) bf16, pad rows zero.
// ---------------------------------------------------------------------------
__global__ __launch_bounds__(256) void wcvt(
    const float* __restrict__ W, u16* __restrict__ Wt, int Nout)
{
    __shared__ float t[32][33];
    int n0 = blockIdx.x * 32, k0 = blockIdx.y * 32;
    int tx = threadIdx.x & 31, ty = threadIdx.x >> 5;
#pragma unroll
    for (int i = 0; i < 4; i++) {
        int k = k0 + ty + i * 8, n = n0 + tx;
        t[ty + i * 8][tx] = (n < Nout) ? W[(size_t)k * Nout + n] : 0.f;
    }
    __syncthreads();
#pragma unroll
    for (int i = 0; i < 4; i++) {
        int n = n0 + ty + i * 8, k = k0 + tx;
        Wt[(size_t)n * 512 + k] = f2bf(t[tx][ty + i * 8]);
    }
}

// ---------------------------------------------------------------------------
// LayerNorm over C with implicit (B,C,N)->(B,N,C) transpose; bf16 output.
// ---------------------------------------------------------------------------
__global__ __launch_bounds__(256) void ln_transpose_kernel(
    const float* __restrict__ fq, const float* __restrict__ gamma,
    const float* __restrict__ beta, u16* __restrict__ q)
{
    int bn = blockIdx.x;
    int b = bn / NTOK, n = bn - b * NTOK;
    const float* src = fq + (size_t)b * C_DIM * NTOK + n;
    int tid = threadIdx.x;
    float x0 = src[(size_t)tid * NTOK];
    float x1 = src[(size_t)(tid + 256) * NTOK];
    float s = x0 + x1, ss = x0 * x0 + x1 * x1;
#pragma unroll
    for (int o = 32; o > 0; o >>= 1) {
        s += __shfl_down(s, o);
        ss += __shfl_down(ss, o);
    }
    __shared__ float sS[4], sQ[4];
    int wid = tid >> 6, lane = tid & 63;
    if (lane == 0) { sS[wid] = s; sQ[wid] = ss; }
    __syncthreads();
    float S = sS[0] + sS[1] + sS[2] + sS[3];
    float SQ = sQ[0] + sQ[1] + sQ[2] + sQ[3];
    float mu = S * (1.0f / 512.0f);
    float var = SQ * (1.0f / 512.0f) - mu * mu;
    float rs = rsqrtf(var + 1e-5f);
    u16* dst = q + (size_t)bn * C_DIM;
    dst[tid]       = f2bf((x0 - mu) * rs * gamma[tid]       + beta[tid]);
    dst[tid + 256] = f2bf((x1 - mu) * rs * gamma[tid + 256] + beta[tid + 256]);
}

// ---------------------------------------------------------------------------
// bf16 MFMA GEMM (m97 structure): C[M,Nout] = A[M,512] @ Bt[N,512]^T + bias.
// 128x128 tile, BK=32, 4 waves x (4x4) mfma_f32_16x16x32_bf16.
// mode 0: fp32 row-major (ldc), bias[col]
// mode 1: bf16 row-major (ldc), bias[col]
// mode 2: fp32 direct (B,C,N) store — rows are channels, cols are tokens;
//         bias[row]; idx = ((b*512 + row)*8000 + token%8000).
// ---------------------------------------------------------------------------
__global__ __launch_bounds__(256) void gemm_bf16(
    const u16* __restrict__ A, const u16* __restrict__ Bt,
    const float* __restrict__ bias, float* __restrict__ Cf,
    u16* __restrict__ Cb, int Nout, int ldc, int relu, int mode)
{
    __shared__ u16 As[128 * 32];
    __shared__ u16 Bs[128 * 32];
    int tid = threadIdx.x, lane = tid & 63, wv = tid >> 6;
    int bm = blockIdx.y * 128, bn = blockIdx.x * 128;
    int wm = (wv >> 1) * 64, wn = (wv & 1) * 64;

    f32x4 acc[4][4];
#pragma unroll
    for (int i = 0; i < 4; i++)
#pragma unroll
        for (int j = 0; j < 4; j++) acc[i][j] = (f32x4){0.f, 0.f, 0.f, 0.f};

    int ci0 = wv * 2, ci1 = wv * 2 + 1;
    int lin0 = ci0 * 64 + lane, lin1 = ci1 * 64 + lane;
    int rA0 = lin0 >> 2, sA0 = (lin0 & 3) ^ ((rA0 >> 1) & 3);
    int rA1 = lin1 >> 2, sA1 = (lin1 & 3) ^ ((rA1 >> 1) & 3);

    const u16* Ab = A + (size_t)bm * 512;
    const u16* Bb = Bt + (size_t)bn * 512;

    int ml = lane & 15, quad = lane >> 4;
    int offA[4], offB[4];
#pragma unroll
    for (int i = 0; i < 4; i++) {
        int r = wm + i * 16 + ml;
        offA[i] = r * 32 + (quad ^ ((r >> 1) & 3)) * 8;
        int rb = wn + i * 16 + ml;
        offB[i] = rb * 32 + (quad ^ ((rb >> 1) & 3)) * 8;
    }

    for (int k0 = 0; k0 < 512; k0 += 32) {
        async16(Ab + (size_t)rA0 * 512 + k0 + sA0 * 8, As + ci0 * 512);
        async16(Ab + (size_t)rA1 * 512 + k0 + sA1 * 8, As + ci1 * 512);
        async16(Bb + (size_t)rA0 * 512 + k0 + sA0 * 8, Bs + ci0 * 512);
        async16(Bb + (size_t)rA1 * 512 + k0 + sA1 * 8, Bs + ci1 * 512);
        __syncthreads();

        bf16x8 af[4], bfr[4];
#pragma unroll
        for (int i = 0; i < 4; i++) {
            af[i]  = *reinterpret_cast<const bf16x8*>(As + offA[i]);
            bfr[i] = *reinterpret_cast<const bf16x8*>(Bs + offB[i]);
        }
#pragma unroll
        for (int i = 0; i < 4; i++)
#pragma unroll
            for (int j = 0; j < 4; j++)
                acc[i][j] = __builtin_amdgcn_mfma_f32_16x16x32_bf16(
                    af[i], bfr[j], acc[i][j], 0, 0, 0);
        __syncthreads();
    }

    // epilogue: C/D layout col=lane&15, row=quad*4+reg (m89/m91 verified)
#pragma unroll
    for (int i = 0; i < 4; i++) {
        int row = bm + wm + i * 16 + quad * 4;
#pragma unroll
        for (int j = 0; j < 4; j++) {
            int col = bn + wn + j * 16 + ml;
            if (col < Nout) {
                float bia = (mode == 2) ? 0.f : bias[col];
#pragma unroll
                for (int rg = 0; rg < 4; rg++) {
                    float v = acc[i][j][rg] + ((mode == 2) ? bias[row + rg] : bia);
                    if (relu) v = fmaxf(v, 0.f);
                    if (mode == 2) {
                        int bb = col >= 8000;
                        int nn = col - bb * 8000;
                        Cf[((size_t)(bb * 512 + row + rg)) * 8000 + nn] = v;
                    } else {
                        size_t idx = (size_t)(row + rg) * ldc + col;
                        if (mode == 1) Cb[idx] = f2bf(v);
                        else           Cf[idx] = v;
                    }
                }
            }
        }
    }
}

// ---------------------------------------------------------------------------
// Fused softmax + offset clip + trilinear sample + einsum.
// One wave handles 4 heads of one token: lane = (head_in_group<<4) | chan4,
// each lane covers 4 channels via float4 corner loads (16 lanes x 16B = 256B
// contiguous per head per corner). attn weight folded into corner weights.
// Reference quirk: off-ch0 -> W(x) axis, ch1 -> H(y), ch2 -> D(z); H=W=D=20
// collapses normalization to clip(base+off, 0, 19).
// ---------------------------------------------------------------------------
__global__ __launch_bounds__(256) void sample_kernel(
    const float* __restrict__ vol, const float* __restrict__ offb,
    const float* __restrict__ lgb, u16* __restrict__ outp)
{
    int wid = threadIdx.x >> 6, lane = threadIdx.x & 63;
    int gw = blockIdx.x * 4 + wid;       // 0 .. BN_TOK*2-1
    int bn = gw >> 1, hp = gw & 1;
    int hg = lane >> 4, cq = lane & 15;
    int h = hp * 4 + hg;
    int b = bn / NTOK, n = bn - b * NTOK;
    int y = n / 400;
    int r2 = n - y * 400;
    int x = r2 / 20;
    int z = r2 - x * 20;

    const float* op = offb + (size_t)bn * 96 + h * 12;
    const float* lp = lgb + (size_t)bn * 32 + h * 4;
    float l0 = lp[0], l1 = lp[1], l2 = lp[2], l3 = lp[3];
    float mx = fmaxf(fmaxf(l0, l1), fmaxf(l2, l3));
    float e0 = expf(l0 - mx), e1 = expf(l1 - mx), e2 = expf(l2 - mx), e3 = expf(l3 - mx);
    float inv = 1.f / (e0 + e1 + e2 + e3);
    float at[4] = {e0 * inv, e1 * inv, e2 * inv, e3 * inv};

    const float* volb = vol + (size_t)b * NTOK * C_DIM + h * HDIM + cq * 4;
    float4 acc = make_float4(0.f, 0.f, 0.f, 0.f);
#pragma unroll
    for (int p = 0; p < 4; p++) {
        float o0 = fminf(fmaxf(op[p * 3 + 0], -3.f), 3.f);
        float o1 = fminf(fmaxf(op[p * 3 + 1], -3.f), 3.f);
        float o2 = fminf(fmaxf(op[p * 3 + 2], -3.f), 3.f);
        float ix = fminf(fmaxf((float)y + o0, 0.f), 19.f);  // W axis
        float iy = fminf(fmaxf((float)x + o1, 0.f), 19.f);  // H axis
        float iz = fminf(fmaxf((float)z + o2, 0.f), 19.f);  // D axis
        float xf = floorf(ix), yf = floorf(iy), zf = floorf(iz);
        float fx = ix - xf, fy = iy - yf, fz = iz - zf;
        int x0 = (int)xf, y0 = (int)yf, z0 = (int)zf;
        int x1 = imin(x0 + 1, 19), y1 = imin(y0 + 1, 19), z1 = imin(z0 + 1, 19);
        // spatial = yi*400 + xi*20 + zi, channels contiguous (stride C_DIM)
        int s00 = y0 * 400 + x0 * 20, s01 = y0 * 400 + x1 * 20;
        int s10 = y1 * 400 + x0 * 20, s11 = y1 * 400 + x1 * 20;
        const float4* p000 = (const float4*)(volb + (size_t)(s00 + z0) * C_DIM);
        const float4* p001 = (const float4*)(volb + (size_t)(s01 + z0) * C_DIM);
        const float4* p010 = (const float4*)(volb + (size_t)(s10 + z0) * C_DIM);
        const float4* p011 = (const float4*)(volb + (size_t)(s11 + z0) * C_DIM);
        const float4* p100 = (const float4*)(volb + (size_t)(s00 + z1) * C_DIM);
        const float4* p101 = (const float4*)(volb + (size_t)(s01 + z1) * C_DIM);
        const float4* p110 = (const float4*)(volb + (size_t)(s10 + z1) * C_DIM);
        const float4* p111 = (const float4*)(volb + (size_t)(s11 + z1) * C_DIM);
        float4 v000 = *p000, v001 = *p001, v010 = *p010, v011 = *p011;
        float4 v100 = *p100, v101 = *p101, v110 = *p110, v111 = *p111;
        // fold attn weight into trilinear weights
        float wz0 = (1.f - fz) * at[p], wz1 = fz * at[p];
        float w00 = wz0 * (1.f - fy), w01 = wz0 * fy;
        float w10 = wz1 * (1.f - fy), w11 = wz1 * fy;
        float gx0 = 1.f - fx;
        fma4(acc, v000, w00 * gx0); fma4(acc, v001, w00 * fx);
        fma4(acc, v010, w01 * gx0); fma4(acc, v011, w01 * fx);
        fma4(acc, v100, w10 * gx0); fma4(acc, v101, w10 * fx);
        fma4(acc, v110, w11 * gx0); fma4(acc, v111, w11 * fx);
    }
    ushort4 o;
    o.x = f2bf(acc.x); o.y = f2bf(acc.y); o.z = f2bf(acc.z); o.w = f2bf(acc.w);
    *reinterpret_cast<ushort4*>(outp + (size_t)bn * C_DIM + h * HDIM + cq * 4) = o;
}

// ---------------------------------------------------------------------------
// Launch
// ---------------------------------------------------------------------------
extern "C" void kernel_launch(void* const* d_in, const int* in_sizes, int n_in,
                              void* d_out, int out_size, void* d_ws, size_t ws_size,
                              hipStream_t stream)
{
    const float* f_query = (const float*)d_in[0];
    const float* f_kv    = (const float*)d_in[1];
    const float* ln_g    = (const float*)d_in[2];
    const float* ln_b    = (const float*)d_in[3];
    const float* Wq      = (const float*)d_in[4];
    const float* bq      = (const float*)d_in[5];
    const float* Wo1     = (const float*)d_in[6];
    const float* bo1     = (const float*)d_in[7];
    const float* Wo2     = (const float*)d_in[8];
    const float* bo2     = (const float*)d_in[9];
    const float* Wa      = (const float*)d_in[10];
    const float* ba      = (const float*)d_in[11];
    const float* Wout    = (const float*)d_in[12];
    const float* bout    = (const float*)d_in[13];
    float* out = (float*)d_out;

    float* ws = (float*)d_ws;
    float* kvT  = ws;                 // 8,192,000 f (kv channels-last)
    float* offb = ws + 8192000;       // 1,536,000 f
    float* lgb  = ws + 9728000;       //   512,000 f
    u16* bws   = (u16*)(ws + 10240000);
    u16* qb    = bws;                 // 8,192,000 bf16 (q; later sampled)
    u16* Qb    = bws + 8192000;       // 8,192,000 bf16
    u16* hid   = bws + 16384000;      // 8,192,000 bf16
    u16* WqT   = bws + 24576000;      // 512x512
    u16* Wo1T  = WqT + 262144;
    u16* WoutT = Wo1T + 262144;
    u16* Wo2T  = WoutT + 262144;      // 128x512 (96 valid, pad 0)
    u16* WaT   = Wo2T + 65536;        // 128x512 (32 valid, pad 0)

    dim3 blk(256);
    wcvt<<<dim3(16, 16), blk, 0, stream>>>(Wq,   WqT,   512);
    wcvt<<<dim3(16, 16), blk, 0, stream>>>(Wo1,  Wo1T,  512);
    wcvt<<<dim3(16, 16), blk, 0, stream>>>(Wout, WoutT, 512);
    wcvt<<<dim3(4, 16),  blk, 0, stream>>>(Wo2,  Wo2T,  96);
    wcvt<<<dim3(4, 16),  blk, 0, stream>>>(Wa,   WaT,   32);
    // f_kv (B,C,N) -> kvT (B,N,C) fp32
    transpose_rs<<<dim3(250, 16, 2), blk, 0, stream>>>(f_kv, kvT, 512, 8000);
    // q = LN(transpose(f_query)) -> bf16
    ln_transpose_kernel<<<dim3(BN_TOK), blk, 0, stream>>>(f_query, ln_g, ln_b, qb);
    // Q = q @ Wq + bq -> bf16
    gemm_bf16<<<dim3(4, 125), blk, 0, stream>>>(qb, WqT, bq, nullptr, Qb, 512, 512, 0, 1);
    // hidden = relu(Q @ Wo1 + bo1) -> bf16
    gemm_bf16<<<dim3(4, 125), blk, 0, stream>>>(Qb, Wo1T, bo1, nullptr, hid, 512, 512, 1, 1);
    // off = hidden @ Wo2 + bo2 -> fp32
    gemm_bf16<<<dim3(1, 125), blk, 0, stream>>>(hid, Wo2T, bo2, offb, nullptr, 96, 96, 0, 0);
    // logits = Q @ Wa + ba -> fp32
    gemm_bf16<<<dim3(1, 125), blk, 0, stream>>>(Qb, WaT, ba, lgb, nullptr, 32, 32, 0, 0);
    // fused sample/softmax/einsum -> qb (bf16)
    sample_kernel<<<dim3(BN_TOK * 2 / 4), blk, 0, stream>>>(kvT, offb, lgb, qb);
    // out(B,C,N) = (sampled @ Wout + bout)^T  via  WoutT @ sampled^T, mode 2
    gemm_bf16<<<dim3(125, 4), blk, 0, stream>>>(WoutT, qb, bout, out, nullptr, 16000, 0, 0, 2);
}

// Round 4
// 278.036 us; speedup vs baseline: 2.7584x; 1.2713x over previous
//
#include <hip/hip_runtime.h>
#include <math.h>

// Problem constants
#define C_DIM 512
#define NHEAD 8
#define HDIM 64
#define NTOK 8000
#define BN_TOK 16000

typedef __attribute__((ext_vector_type(8))) short bf16x8;
typedef __attribute__((ext_vector_type(4))) float f32x4;
typedef unsigned short u16;

__device__ __forceinline__ int imin(int a, int b) { return a < b ? a : b; }

// fp32 -> bf16 round-to-nearest-even
__device__ __forceinline__ u16 f2bf(float x) {
    union { float f; unsigned u; } c; c.f = x;
    unsigned r = c.u + 0x7FFFu + ((c.u >> 16) & 1u);
    return (u16)(r >> 16);
}

// async global->LDS, 16 bytes per lane (global_load_lds_dwordx4)
__device__ __forceinline__ void async16(const void* g, void* l) {
    __builtin_amdgcn_global_load_lds(
        (const __attribute__((address_space(1))) void*)g,
        (__attribute__((address_space(3))) void*)l, 16, 0, 0);
}

__device__ __forceinline__ void fma4(float4& a, const float4& v, float w) {
    a.x = fmaf(v.x, w, a.x);
    a.y = fmaf(v.y, w, a.y);
    a.z = fmaf(v.z, w, a.z);
    a.w = fmaf(v.w, w, a.w);
}

// ---------------------------------------------------------------------------
// Tiled fp32 transpose: in (R,S) -> out (S,R), batched over z.
// ---------------------------------------------------------------------------
__global__ __launch_bounds__(256) void transpose_rs(
    const float* __restrict__ in, float* __restrict__ out, int R, int S)
{
    __shared__ float tile[32][33];
    int b = blockIdx.z;
    const float* inb = in + (size_t)b * R * S;
    float* outb = out + (size_t)b * R * S;
    int s0 = blockIdx.x * 32, r0 = blockIdx.y * 32;
    int tx = threadIdx.x & 31, ty = threadIdx.x >> 5;
#pragma unroll
    for (int i = 0; i < 4; i++) {
        int r = r0 + ty + i * 8, s = s0 + tx;
        if (r < R && s < S) tile[ty + i * 8][tx] = inb[(size_t)r * S + s];
    }
    __syncthreads();
#pragma unroll
    for (int i = 0; i < 4; i++) {
        int s = s0 + ty + i * 8, r = r0 + tx;
        if (r < R && s < S) outb[(size_t)s * R + r] = tile[tx][ty + i * 8];
    }
}

// ---------------------------------------------------------------------------
// Merged weight converts: z selects which W (512 x Nout) fp32 -> (Npad x 512)
// bf16, pad rows zeroed. Grid (16,16,5); small weights early-out on x.
// ---------------------------------------------------------------------------
__global__ __launch_bounds__(256) void wcvt_all(
    const float* __restrict__ W0, u16* __restrict__ T0,
    const float* __restrict__ W1, u16* __restrict__ T1,
    const float* __restrict__ W2, u16* __restrict__ T2,
    const float* __restrict__ W3, u16* __restrict__ T3,
    const float* __restrict__ W4, u16* __restrict__ T4)
{
    const float* W; u16* Wt; int Nout, Npad;
    switch (blockIdx.z) {
        case 0: W = W0; Wt = T0; Nout = 512; Npad = 512; break;
        case 1: W = W1; Wt = T1; Nout = 512; Npad = 512; break;
        case 2: W = W2; Wt = T2; Nout = 512; Npad = 512; break;
        case 3: W = W3; Wt = T3; Nout = 96;  Npad = 128; break;
        default: W = W4; Wt = T4; Nout = 32; Npad = 128; break;
    }
    int n0 = blockIdx.x * 32, k0 = blockIdx.y * 32;
    if (n0 >= Npad) return;
    __shared__ float t[32][33];
    int tx = threadIdx.x & 31, ty = threadIdx.x >> 5;
#pragma unroll
    for (int i = 0; i < 4; i++) {
        int k = k0 + ty + i * 8, n = n0 + tx;
        t[ty + i * 8][tx] = (n < Nout) ? W[(size_t)k * Nout + n] : 0.f;
    }
    __syncthreads();
#pragma unroll
    for (int i = 0; i < 4; i++) {
        int n = n0 + ty + i * 8, k = k0 + tx;
        Wt[(size_t)n * 512 + k] = f2bf(t[tx][ty + i * 8]);
    }
}

// ---------------------------------------------------------------------------
// Fused LayerNorm + (B,C,N)->(B,N,C) transpose, LDS-tiled for ideal fetch.
// Block = 32 tokens x 512 channels. Phase 1: coalesced float2 reads along N
// into tile[c][t] (+1 pad; writes conflict-free), accumulating sum/sumsq.
// Phase 2: per-token mu/rs from LDS reduction, token-major reads, contiguous
// 512B bf16 wave stores. Each HBM line of f_query fetched exactly once.
// ---------------------------------------------------------------------------
__global__ __launch_bounds__(256) void ln_fused(
    const float* __restrict__ fq, const float* __restrict__ gamma,
    const float* __restrict__ beta, u16* __restrict__ q)
{
    __shared__ float tile[512][33];   // [c][t], 67.6 KB
    __shared__ float ps[32][17], pq[32][17];
    __shared__ float muA[32], rsA[32];
    int blk = blockIdx.x;
    int b = blk / 250;
    int n0 = (blk - b * 250) * 32;
    const float* src = fq + (size_t)b * C_DIM * NTOK + n0;
    int tid = threadIdx.x;
    int cgrp = tid >> 4;          // 0..15
    int tp = (tid & 15) * 2;      // 0,2,..,30
    float s0 = 0.f, q0 = 0.f, s1 = 0.f, q1 = 0.f;
#pragma unroll 4
    for (int it = 0; it < 32; ++it) {
        int c = it * 16 + cgrp;
        float2 v = *reinterpret_cast<const float2*>(src + (size_t)c * NTOK + tp);
        tile[c][tp] = v.x; tile[c][tp + 1] = v.y;
        s0 += v.x; q0 += v.x * v.x;
        s1 += v.y; q1 += v.y * v.y;
    }
    ps[tp][cgrp] = s0; pq[tp][cgrp] = q0;
    ps[tp + 1][cgrp] = s1; pq[tp + 1][cgrp] = q1;
    // preload gamma/beta for this lane's channels (both halves)
    int lane = tid & 63, wv = tid >> 6;
    float4 g0 = *reinterpret_cast<const float4*>(gamma + lane * 4);
    float4 be0 = *reinterpret_cast<const float4*>(beta + lane * 4);
    float4 g1 = *reinterpret_cast<const float4*>(gamma + 256 + lane * 4);
    float4 be1 = *reinterpret_cast<const float4*>(beta + 256 + lane * 4);
    __syncthreads();
    if (tid < 32) {
        float S = 0.f, SQ = 0.f;
#pragma unroll
        for (int g = 0; g < 16; ++g) { S += ps[tid][g]; SQ += pq[tid][g]; }
        float mu = S * (1.f / 512.f);
        float var = SQ * (1.f / 512.f) - mu * mu;
        muA[tid] = mu;
        rsA[tid] = rsqrtf(var + 1e-5f);
    }
    __syncthreads();
#pragma unroll
    for (int it = 0; it < 16; ++it) {
        int task = it * 4 + wv;     // 0..63 : (token, half)
        int t = task >> 1, h = task & 1;
        int c0 = h * 256 + lane * 4;
        float mu = muA[t], rs = rsA[t];
        float4 g = h ? g1 : g0, bb = h ? be1 : be0;
        ushort4 o;
        o.x = f2bf((tile[c0 + 0][t] - mu) * rs * g.x + bb.x);
        o.y = f2bf((tile[c0 + 1][t] - mu) * rs * g.y + bb.y);
        o.z = f2bf((tile[c0 + 2][t] - mu) * rs * g.z + bb.z);
        o.w = f2bf((tile[c0 + 3][t] - mu) * rs * g.w + bb.w);
        *reinterpret_cast<ushort4*>(q + ((size_t)(b * NTOK + n0 + t)) * C_DIM + c0) = o;
    }
}

// ---------------------------------------------------------------------------
// bf16 MFMA GEMM body (m97 structure): C[M,Nout] = A[M,512] @ Bt[.,512]^T.
// 128x128 tile, BK=32, 4 waves x (4x4) mfma_f32_16x16x32_bf16.
// mode 0: fp32 row-major (ldc), bias[col]
// mode 1: bf16 row-major (ldc), bias[col]
// mode 2: fp32 direct (B,C,N) store — rows=channels, cols=tokens; bias[row].
// ---------------------------------------------------------------------------
__device__ __forceinline__ void gemm_body(
    const u16* __restrict__ A, const u16* __restrict__ Bt,
    const float* __restrict__ bias, float* __restrict__ Cf,
    u16* __restrict__ Cb, int Nout, int ldc, int relu, int mode,
    int bx, int by)
{
    __shared__ u16 As[128 * 32];
    __shared__ u16 Bs[128 * 32];
    int tid = threadIdx.x, lane = tid & 63, wv = tid >> 6;
    int bm = by * 128, bn = bx * 128;
    int wm = (wv >> 1) * 64, wn = (wv & 1) * 64;

    f32x4 acc[4][4];
#pragma unroll
    for (int i = 0; i < 4; i++)
#pragma unroll
        for (int j = 0; j < 4; j++) acc[i][j] = (f32x4){0.f, 0.f, 0.f, 0.f};

    int ci0 = wv * 2, ci1 = wv * 2 + 1;
    int lin0 = ci0 * 64 + lane, lin1 = ci1 * 64 + lane;
    int rA0 = lin0 >> 2, sA0 = (lin0 & 3) ^ ((rA0 >> 1) & 3);
    int rA1 = lin1 >> 2, sA1 = (lin1 & 3) ^ ((rA1 >> 1) & 3);

    const u16* Ab = A + (size_t)bm * 512;
    const u16* Bb = Bt + (size_t)bn * 512;

    int ml = lane & 15, quad = lane >> 4;
    int offA[4], offB[4];
#pragma unroll
    for (int i = 0; i < 4; i++) {
        int r = wm + i * 16 + ml;
        offA[i] = r * 32 + (quad ^ ((r >> 1) & 3)) * 8;
        int rb = wn + i * 16 + ml;
        offB[i] = rb * 32 + (quad ^ ((rb >> 1) & 3)) * 8;
    }

    for (int k0 = 0; k0 < 512; k0 += 32) {
        async16(Ab + (size_t)rA0 * 512 + k0 + sA0 * 8, As + ci0 * 512);
        async16(Ab + (size_t)rA1 * 512 + k0 + sA1 * 8, As + ci1 * 512);
        async16(Bb + (size_t)rA0 * 512 + k0 + sA0 * 8, Bs + ci0 * 512);
        async16(Bb + (size_t)rA1 * 512 + k0 + sA1 * 8, Bs + ci1 * 512);
        __syncthreads();

        bf16x8 af[4], bfr[4];
#pragma unroll
        for (int i = 0; i < 4; i++) {
            af[i]  = *reinterpret_cast<const bf16x8*>(As + offA[i]);
            bfr[i] = *reinterpret_cast<const bf16x8*>(Bs + offB[i]);
        }
#pragma unroll
        for (int i = 0; i < 4; i++)
#pragma unroll
            for (int j = 0; j < 4; j++)
                acc[i][j] = __builtin_amdgcn_mfma_f32_16x16x32_bf16(
                    af[i], bfr[j], acc[i][j], 0, 0, 0);
        __syncthreads();
    }

    // epilogue: C/D layout col=lane&15, row=quad*4+reg (m89/m91 verified)
#pragma unroll
    for (int i = 0; i < 4; i++) {
        int row = bm + wm + i * 16 + quad * 4;
#pragma unroll
        for (int j = 0; j < 4; j++) {
            int col = bn + wn + j * 16 + ml;
            if (col < Nout) {
                float bia = (mode == 2) ? 0.f : bias[col];
#pragma unroll
                for (int rg = 0; rg < 4; rg++) {
                    float v = acc[i][j][rg] + ((mode == 2) ? bias[row + rg] : bia);
                    if (relu) v = fmaxf(v, 0.f);
                    if (mode == 2) {
                        int bb = col >= 8000;
                        int nn = col - bb * 8000;
                        Cf[((size_t)(bb * 512 + row + rg)) * 8000 + nn] = v;
                    } else {
                        size_t idx = (size_t)(row + rg) * ldc + col;
                        if (mode == 1) Cb[idx] = f2bf(v);
                        else           Cf[idx] = v;
                    }
                }
            }
        }
    }
}

__global__ __launch_bounds__(256) void gemm_bf16(
    const u16* __restrict__ A, const u16* __restrict__ Bt,
    const float* __restrict__ bias, float* __restrict__ Cf,
    u16* __restrict__ Cb, int Nout, int ldc, int relu, int mode)
{
    gemm_body(A, Bt, bias, Cf, Cb, Nout, ldc, relu, mode,
              blockIdx.x, blockIdx.y);
}

// Two independent small GEMMs in one dispatch (z selects operand set).
__global__ __launch_bounds__(256) void gemm_dual(
    const u16* __restrict__ A0, const u16* __restrict__ B0,
    const float* __restrict__ bias0, float* __restrict__ C0, int N0,
    const u16* __restrict__ A1, const u16* __restrict__ B1,
    const float* __restrict__ bias1, float* __restrict__ C1, int N1)
{
    if (blockIdx.z == 0)
        gemm_body(A0, B0, bias0, C0, nullptr, N0, N0, 0, 0, blockIdx.x, blockIdx.y);
    else
        gemm_body(A1, B1, bias1, C1, nullptr, N1, N1, 0, 0, blockIdx.x, blockIdx.y);
}

// ---------------------------------------------------------------------------
// Fused softmax + offset clip + trilinear sample + einsum.
// One wave handles 4 heads of one token: lane = (head_in_group<<4) | chan4,
// each lane covers 4 channels via float4 corner loads. attn weight folded
// into corner weights. Reference quirk: off-ch0 -> W(x) axis, ch1 -> H(y),
// ch2 -> D(z); H=W=D=20 collapses normalization to clip(base+off, 0, 19).
// ---------------------------------------------------------------------------
__global__ __launch_bounds__(256) void sample_kernel(
    const float* __restrict__ vol, const float* __restrict__ offb,
    const float* __restrict__ lgb, u16* __restrict__ outp)
{
    int wid = threadIdx.x >> 6, lane = threadIdx.x & 63;
    int gw = blockIdx.x * 4 + wid;       // 0 .. BN_TOK*2-1
    int bn = gw >> 1, hp = gw & 1;
    int hg = lane >> 4, cq = lane & 15;
    int h = hp * 4 + hg;
    int b = bn / NTOK, n = bn - b * NTOK;
    int y = n / 400;
    int r2 = n - y * 400;
    int x = r2 / 20;
    int z = r2 - x * 20;

    const float* op = offb + (size_t)bn * 96 + h * 12;
    const float* lp = lgb + (size_t)bn * 32 + h * 4;
    float l0 = lp[0], l1 = lp[1], l2 = lp[2], l3 = lp[3];
    float mx = fmaxf(fmaxf(l0, l1), fmaxf(l2, l3));
    float e0 = expf(l0 - mx), e1 = expf(l1 - mx), e2 = expf(l2 - mx), e3 = expf(l3 - mx);
    float inv = 1.f / (e0 + e1 + e2 + e3);
    float at[4] = {e0 * inv, e1 * inv, e2 * inv, e3 * inv};

    const float* volb = vol + (size_t)b * NTOK * C_DIM + h * HDIM + cq * 4;
    float4 acc = make_float4(0.f, 0.f, 0.f, 0.f);
#pragma unroll
    for (int p = 0; p < 4; p++) {
        float o0 = fminf(fmaxf(op[p * 3 + 0], -3.f), 3.f);
        float o1 = fminf(fmaxf(op[p * 3 + 1], -3.f), 3.f);
        float o2 = fminf(fmaxf(op[p * 3 + 2], -3.f), 3.f);
        float ix = fminf(fmaxf((float)y + o0, 0.f), 19.f);  // W axis
        float iy = fminf(fmaxf((float)x + o1, 0.f), 19.f);  // H axis
        float iz = fminf(fmaxf((float)z + o2, 0.f), 19.f);  // D axis
        float xf = floorf(ix), yf = floorf(iy), zf = floorf(iz);
        float fx = ix - xf, fy = iy - yf, fz = iz - zf;
        int x0 = (int)xf, y0 = (int)yf, z0 = (int)zf;
        int x1 = imin(x0 + 1, 19), y1 = imin(y0 + 1, 19), z1 = imin(z0 + 1, 19);
        int s00 = y0 * 400 + x0 * 20, s01 = y0 * 400 + x1 * 20;
        int s10 = y1 * 400 + x0 * 20, s11 = y1 * 400 + x1 * 20;
        float4 v000 = *(const float4*)(volb + (size_t)(s00 + z0) * C_DIM);
        float4 v001 = *(const float4*)(volb + (size_t)(s01 + z0) * C_DIM);
        float4 v010 = *(const float4*)(volb + (size_t)(s10 + z0) * C_DIM);
        float4 v011 = *(const float4*)(volb + (size_t)(s11 + z0) * C_DIM);
        float4 v100 = *(const float4*)(volb + (size_t)(s00 + z1) * C_DIM);
        float4 v101 = *(const float4*)(volb + (size_t)(s01 + z1) * C_DIM);
        float4 v110 = *(const float4*)(volb + (size_t)(s10 + z1) * C_DIM);
        float4 v111 = *(const float4*)(volb + (size_t)(s11 + z1) * C_DIM);
        float wz0 = (1.f - fz) * at[p], wz1 = fz * at[p];
        float w00 = wz0 * (1.f - fy), w01 = wz0 * fy;
        float w10 = wz1 * (1.f - fy), w11 = wz1 * fy;
        float gx0 = 1.f - fx;
        fma4(acc, v000, w00 * gx0); fma4(acc, v001, w00 * fx);
        fma4(acc, v010, w01 * gx0); fma4(acc, v011, w01 * fx);
        fma4(acc, v100, w10 * gx0); fma4(acc, v101, w10 * fx);
        fma4(acc, v110, w11 * gx0); fma4(acc, v111, w11 * fx);
    }
    ushort4 o;
    o.x = f2bf(acc.x); o.y = f2bf(acc.y); o.z = f2bf(acc.z); o.w = f2bf(acc.w);
    *reinterpret_cast<ushort4*>(outp + (size_t)bn * C_DIM + h * HDIM + cq * 4) = o;
}

// ---------------------------------------------------------------------------
// Launch
// ---------------------------------------------------------------------------
extern "C" void kernel_launch(void* const* d_in, const int* in_sizes, int n_in,
                              void* d_out, int out_size, void* d_ws, size_t ws_size,
                              hipStream_t stream)
{
    const float* f_query = (const float*)d_in[0];
    const float* f_kv    = (const float*)d_in[1];
    const float* ln_g    = (const float*)d_in[2];
    const float* ln_b    = (const float*)d_in[3];
    const float* Wq      = (const float*)d_in[4];
    const float* bq      = (const float*)d_in[5];
    const float* Wo1     = (const float*)d_in[6];
    const float* bo1     = (const float*)d_in[7];
    const float* Wo2     = (const float*)d_in[8];
    const float* bo2     = (const float*)d_in[9];
    const float* Wa      = (const float*)d_in[10];
    const float* ba      = (const float*)d_in[11];
    const float* Wout    = (const float*)d_in[12];
    const float* bout    = (const float*)d_in[13];
    float* out = (float*)d_out;

    float* ws = (float*)d_ws;
    float* kvT  = ws;                 // 8,192,000 f (kv channels-last)
    float* offb = ws + 8192000;       // 1,536,000 f
    float* lgb  = ws + 9728000;       //   512,000 f
    u16* bws   = (u16*)(ws + 10240000);
    u16* qb    = bws;                 // 8,192,000 bf16 (q; later sampled)
    u16* Qb    = bws + 8192000;       // 8,192,000 bf16
    u16* hid   = bws + 16384000;      // 8,192,000 bf16
    u16* WqT   = bws + 24576000;      // 512x512
    u16* Wo1T  = WqT + 262144;
    u16* WoutT = Wo1T + 262144;
    u16* Wo2T  = WoutT + 262144;      // 128x512 (96 valid, pad 0)
    u16* WaT   = Wo2T + 65536;        // 128x512 (32 valid, pad 0)

    dim3 blk(256);
    // all weight transpose-converts in one dispatch
    wcvt_all<<<dim3(16, 16, 5), blk, 0, stream>>>(
        Wq, WqT, Wo1, Wo1T, Wout, WoutT, Wo2, Wo2T, Wa, WaT);
    // f_kv (B,C,N) -> kvT (B,N,C) fp32
    transpose_rs<<<dim3(250, 16, 2), blk, 0, stream>>>(f_kv, kvT, 512, 8000);
    // q = LN(transpose(f_query)) -> bf16, fused LDS tile
    ln_fused<<<dim3(500), blk, 0, stream>>>(f_query, ln_g, ln_b, qb);
    // Q = q @ Wq + bq -> bf16
    gemm_bf16<<<dim3(4, 125), blk, 0, stream>>>(qb, WqT, bq, nullptr, Qb, 512, 512, 0, 1);
    // hidden = relu(Q @ Wo1 + bo1) -> bf16
    gemm_bf16<<<dim3(4, 125), blk, 0, stream>>>(Qb, Wo1T, bo1, nullptr, hid, 512, 512, 1, 1);
    // off = hidden @ Wo2 + bo2 (fp32) AND logits = Q @ Wa + ba (fp32), one dispatch
    gemm_dual<<<dim3(1, 125, 2), blk, 0, stream>>>(
        hid, Wo2T, bo2, offb, 96, Qb, WaT, ba, lgb, 32);
    // fused sample/softmax/einsum -> qb (bf16)
    sample_kernel<<<dim3(BN_TOK * 2 / 4), blk, 0, stream>>>(kvT, offb, lgb, qb);
    // out(B,C,N) = (sampled @ Wout + bout)^T  via  WoutT @ sampled^T, mode 2
    gemm_bf16<<<dim3(125, 4), blk, 0, stream>>>(WoutT, qb, bout, out, nullptr, 16000, 0, 0, 2);
}

// Round 5
// 269.423 us; speedup vs baseline: 2.8466x; 1.0320x over previous
//
#include <hip/hip_runtime.h>
#include <math.h>

// Problem constants
#define C_DIM 512
#define NHEAD 8
#define HDIM 64
#define NTOK 8000
#define BN_TOK 16000

typedef __attribute__((ext_vector_type(8))) short bf16x8;
typedef __attribute__((ext_vector_type(4))) float f32x4;
typedef unsigned short u16;

__device__ __forceinline__ int imin(int a, int b) { return a < b ? a : b; }

// fp32 -> bf16 round-to-nearest-even
__device__ __forceinline__ u16 f2bf(float x) {
    union { float f; unsigned u; } c; c.f = x;
    unsigned r = c.u + 0x7FFFu + ((c.u >> 16) & 1u);
    return (u16)(r >> 16);
}

// async global->LDS, 16 bytes per lane (global_load_lds_dwordx4)
__device__ __forceinline__ void async16(const void* g, void* l) {
    __builtin_amdgcn_global_load_lds(
        (const __attribute__((address_space(1))) void*)g,
        (__attribute__((address_space(3))) void*)l, 16, 0, 0);
}

// fma of 4 bf16 channels (packed in uint2, bf16-in-high-half trick) into acc
__device__ __forceinline__ void fmabf(float4& a, uint2 d, float w) {
    a.x = fmaf(__uint_as_float(d.x << 16), w, a.x);
    a.y = fmaf(__uint_as_float(d.x & 0xffff0000u), w, a.y);
    a.z = fmaf(__uint_as_float(d.y << 16), w, a.z);
    a.w = fmaf(__uint_as_float(d.y & 0xffff0000u), w, a.w);
}

// ---------------------------------------------------------------------------
// f_kv (B,C,N) fp32 -> kvT (B,N,C) bf16. Fixed 512 x 8000 per batch.
// Phase 2 writes ushort4 (4 channels) per thread.
// ---------------------------------------------------------------------------
__global__ __launch_bounds__(256) void transpose_c2l_bf16(
    const float* __restrict__ in, u16* __restrict__ out)
{
    __shared__ float tile[32][33];
    int b = blockIdx.z;
    const float* inb = in + (size_t)b * 512 * NTOK;
    u16* outb = out + (size_t)b * NTOK * 512;
    int s0 = blockIdx.x * 32, r0 = blockIdx.y * 32;   // s: token, r: channel
    int tx = threadIdx.x & 31, ty = threadIdx.x >> 5;
#pragma unroll
    for (int i = 0; i < 4; i++)
        tile[ty + i * 8][tx] = inb[(size_t)(r0 + ty + i * 8) * NTOK + s0 + tx];
    __syncthreads();
    int rq = threadIdx.x & 7, sy = threadIdx.x >> 3;  // rq: channel quad, sy: token
    ushort4 o;
    o.x = f2bf(tile[rq * 4 + 0][sy]);
    o.y = f2bf(tile[rq * 4 + 1][sy]);
    o.z = f2bf(tile[rq * 4 + 2][sy]);
    o.w = f2bf(tile[rq * 4 + 3][sy]);
    *reinterpret_cast<ushort4*>(outb + (size_t)(s0 + sy) * 512 + r0 + rq * 4) = o;
}

// ---------------------------------------------------------------------------
// Merged weight converts: z selects which W (512 x Nout) fp32 -> (Npad x 512)
// bf16, pad rows zeroed. Grid (16,16,5); small weights early-out on x.
// ---------------------------------------------------------------------------
__global__ __launch_bounds__(256) void wcvt_all(
    const float* __restrict__ W0, u16* __restrict__ T0,
    const float* __restrict__ W1, u16* __restrict__ T1,
    const float* __restrict__ W2, u16* __restrict__ T2,
    const float* __restrict__ W3, u16* __restrict__ T3,
    const float* __restrict__ W4, u16* __restrict__ T4)
{
    const float* W; u16* Wt; int Nout, Npad;
    switch (blockIdx.z) {
        case 0: W = W0; Wt = T0; Nout = 512; Npad = 512; break;
        case 1: W = W1; Wt = T1; Nout = 512; Npad = 512; break;
        case 2: W = W2; Wt = T2; Nout = 512; Npad = 512; break;
        case 3: W = W3; Wt = T3; Nout = 96;  Npad = 128; break;
        default: W = W4; Wt = T4; Nout = 32; Npad = 128; break;
    }
    int n0 = blockIdx.x * 32, k0 = blockIdx.y * 32;
    if (n0 >= Npad) return;
    __shared__ float t[32][33];
    int tx = threadIdx.x & 31, ty = threadIdx.x >> 5;
#pragma unroll
    for (int i = 0; i < 4; i++) {
        int k = k0 + ty + i * 8, n = n0 + tx;
        t[ty + i * 8][tx] = (n < Nout) ? W[(size_t)k * Nout + n] : 0.f;
    }
    __syncthreads();
#pragma unroll
    for (int i = 0; i < 4; i++) {
        int n = n0 + ty + i * 8, k = k0 + tx;
        Wt[(size_t)n * 512 + k] = f2bf(t[tx][ty + i * 8]);
    }
}

// ---------------------------------------------------------------------------
// Fused LayerNorm + (B,C,N)->(B,N,C) transpose, LDS-tiled for ideal fetch.
// ---------------------------------------------------------------------------
__global__ __launch_bounds__(256) void ln_fused(
    const float* __restrict__ fq, const float* __restrict__ gamma,
    const float* __restrict__ beta, u16* __restrict__ q)
{
    __shared__ float tile[512][33];   // [c][t], 67.6 KB
    __shared__ float ps[32][17], pq[32][17];
    __shared__ float muA[32], rsA[32];
    int blk = blockIdx.x;
    int b = blk / 250;
    int n0 = (blk - b * 250) * 32;
    const float* src = fq + (size_t)b * C_DIM * NTOK + n0;
    int tid = threadIdx.x;
    int cgrp = tid >> 4;          // 0..15
    int tp = (tid & 15) * 2;      // 0,2,..,30
    float s0 = 0.f, q0 = 0.f, s1 = 0.f, q1 = 0.f;
#pragma unroll 4
    for (int it = 0; it < 32; ++it) {
        int c = it * 16 + cgrp;
        float2 v = *reinterpret_cast<const float2*>(src + (size_t)c * NTOK + tp);
        tile[c][tp] = v.x; tile[c][tp + 1] = v.y;
        s0 += v.x; q0 += v.x * v.x;
        s1 += v.y; q1 += v.y * v.y;
    }
    ps[tp][cgrp] = s0; pq[tp][cgrp] = q0;
    ps[tp + 1][cgrp] = s1; pq[tp + 1][cgrp] = q1;
    int lane = tid & 63, wv = tid >> 6;
    float4 g0 = *reinterpret_cast<const float4*>(gamma + lane * 4);
    float4 be0 = *reinterpret_cast<const float4*>(beta + lane * 4);
    float4 g1 = *reinterpret_cast<const float4*>(gamma + 256 + lane * 4);
    float4 be1 = *reinterpret_cast<const float4*>(beta + 256 + lane * 4);
    __syncthreads();
    if (tid < 32) {
        float S = 0.f, SQ = 0.f;
#pragma unroll
        for (int g = 0; g < 16; ++g) { S += ps[tid][g]; SQ += pq[tid][g]; }
        float mu = S * (1.f / 512.f);
        float var = SQ * (1.f / 512.f) - mu * mu;
        muA[tid] = mu;
        rsA[tid] = rsqrtf(var + 1e-5f);
    }
    __syncthreads();
#pragma unroll
    for (int it = 0; it < 16; ++it) {
        int task = it * 4 + wv;     // 0..63 : (token, half)
        int t = task >> 1, h = task & 1;
        int c0 = h * 256 + lane * 4;
        float mu = muA[t], rs = rsA[t];
        float4 g = h ? g1 : g0, bb = h ? be1 : be0;
        ushort4 o;
        o.x = f2bf((tile[c0 + 0][t] - mu) * rs * g.x + bb.x);
        o.y = f2bf((tile[c0 + 1][t] - mu) * rs * g.y + bb.y);
        o.z = f2bf((tile[c0 + 2][t] - mu) * rs * g.z + bb.z);
        o.w = f2bf((tile[c0 + 3][t] - mu) * rs * g.w + bb.w);
        *reinterpret_cast<ushort4*>(q + ((size_t)(b * NTOK + n0 + t)) * C_DIM + c0) = o;
    }
}

// ---------------------------------------------------------------------------
// bf16 MFMA GEMM body (m97 structure): C[M,Nout] = A[M,512] @ Bt[.,512]^T.
// mode 0: fp32 row-major (ldc), bias[col]
// mode 1: bf16 row-major (ldc), bias[col]
// mode 2: fp32 direct (B,C,N) store — rows=channels, cols=tokens; bias[row].
// ---------------------------------------------------------------------------
__device__ __forceinline__ void gemm_body(
    const u16* __restrict__ A, const u16* __restrict__ Bt,
    const float* __restrict__ bias, float* __restrict__ Cf,
    u16* __restrict__ Cb, int Nout, int ldc, int relu, int mode,
    int bx, int by)
{
    __shared__ u16 As[128 * 32];
    __shared__ u16 Bs[128 * 32];
    int tid = threadIdx.x, lane = tid & 63, wv = tid >> 6;
    int bm = by * 128, bn = bx * 128;
    int wm = (wv >> 1) * 64, wn = (wv & 1) * 64;

    f32x4 acc[4][4];
#pragma unroll
    for (int i = 0; i < 4; i++)
#pragma unroll
        for (int j = 0; j < 4; j++) acc[i][j] = (f32x4){0.f, 0.f, 0.f, 0.f};

    int ci0 = wv * 2, ci1 = wv * 2 + 1;
    int lin0 = ci0 * 64 + lane, lin1 = ci1 * 64 + lane;
    int rA0 = lin0 >> 2, sA0 = (lin0 & 3) ^ ((rA0 >> 1) & 3);
    int rA1 = lin1 >> 2, sA1 = (lin1 & 3) ^ ((rA1 >> 1) & 3);

    const u16* Ab = A + (size_t)bm * 512;
    const u16* Bb = Bt + (size_t)bn * 512;

    int ml = lane & 15, quad = lane >> 4;
    int offA[4], offB[4];
#pragma unroll
    for (int i = 0; i < 4; i++) {
        int r = wm + i * 16 + ml;
        offA[i] = r * 32 + (quad ^ ((r >> 1) & 3)) * 8;
        int rb = wn + i * 16 + ml;
        offB[i] = rb * 32 + (quad ^ ((rb >> 1) & 3)) * 8;
    }

    for (int k0 = 0; k0 < 512; k0 += 32) {
        async16(Ab + (size_t)rA0 * 512 + k0 + sA0 * 8, As + ci0 * 512);
        async16(Ab + (size_t)rA1 * 512 + k0 + sA1 * 8, As + ci1 * 512);
        async16(Bb + (size_t)rA0 * 512 + k0 + sA0 * 8, Bs + ci0 * 512);
        async16(Bb + (size_t)rA1 * 512 + k0 + sA1 * 8, Bs + ci1 * 512);
        __syncthreads();

        bf16x8 af[4], bfr[4];
#pragma unroll
        for (int i = 0; i < 4; i++) {
            af[i]  = *reinterpret_cast<const bf16x8*>(As + offA[i]);
            bfr[i] = *reinterpret_cast<const bf16x8*>(Bs + offB[i]);
        }
#pragma unroll
        for (int i = 0; i < 4; i++)
#pragma unroll
            for (int j = 0; j < 4; j++)
                acc[i][j] = __builtin_amdgcn_mfma_f32_16x16x32_bf16(
                    af[i], bfr[j], acc[i][j], 0, 0, 0);
        __syncthreads();
    }

    // epilogue: C/D layout col=lane&15, row=quad*4+reg (m89/m91 verified)
#pragma unroll
    for (int i = 0; i < 4; i++) {
        int row = bm + wm + i * 16 + quad * 4;
#pragma unroll
        for (int j = 0; j < 4; j++) {
            int col = bn + wn + j * 16 + ml;
            if (col < Nout) {
                float bia = (mode == 2) ? 0.f : bias[col];
#pragma unroll
                for (int rg = 0; rg < 4; rg++) {
                    float v = acc[i][j][rg] + ((mode == 2) ? bias[row + rg] : bia);
                    if (relu) v = fmaxf(v, 0.f);
                    if (mode == 2) {
                        int bb = col >= 8000;
                        int nn = col - bb * 8000;
                        Cf[((size_t)(bb * 512 + row + rg)) * 8000 + nn] = v;
                    } else {
                        size_t idx = (size_t)(row + rg) * ldc + col;
                        if (mode == 1) Cb[idx] = f2bf(v);
                        else           Cf[idx] = v;
                    }
                }
            }
        }
    }
}

__global__ __launch_bounds__(256) void gemm_bf16(
    const u16* __restrict__ A, const u16* __restrict__ Bt,
    const float* __restrict__ bias, float* __restrict__ Cf,
    u16* __restrict__ Cb, int Nout, int ldc, int relu, int mode)
{
    gemm_body(A, Bt, bias, Cf, Cb, Nout, ldc, relu, mode,
              blockIdx.x, blockIdx.y);
}

// Two independent small GEMMs in one dispatch (z selects operand set).
__global__ __launch_bounds__(256) void gemm_dual(
    const u16* __restrict__ A0, const u16* __restrict__ B0,
    const float* __restrict__ bias0, float* __restrict__ C0, int N0,
    const u16* __restrict__ A1, const u16* __restrict__ B1,
    const float* __restrict__ bias1, float* __restrict__ C1, int N1)
{
    if (blockIdx.z == 0)
        gemm_body(A0, B0, bias0, C0, nullptr, N0, N0, 0, 0, blockIdx.x, blockIdx.y);
    else
        gemm_body(A1, B1, bias1, C1, nullptr, N1, N1, 0, 0, blockIdx.x, blockIdx.y);
}

// ---------------------------------------------------------------------------
// Fused softmax + offset clip + trilinear sample + einsum, bf16 volume.
// One wave = 4 heads of one token; lane = (head_in_group<<4) | chan4; each
// lane covers 4 channels via uint2 (4 x bf16) corner loads (16 lanes x 8B =
// 128B contiguous per head per corner). attn weight folded into corner
// weights; bf16 unpacked via shift/and into the fma.
// XCD swizzle: blockIdx.x & 7 selects a 2000-token contiguous slab so each
// XCD's L2 holds a ~5 MB sampled footprint instead of streaming the volume.
// Reference quirk: off-ch0 -> W(x) axis, ch1 -> H(y), ch2 -> D(z); H=W=D=20
// collapses normalization to clip(base+off, 0, 19).
// ---------------------------------------------------------------------------
__global__ __launch_bounds__(256) void sample_kernel(
    const u16* __restrict__ vol, const float* __restrict__ offb,
    const float* __restrict__ lgb, u16* __restrict__ outp)
{
    int wid = threadIdx.x >> 6, lane = threadIdx.x & 63;
    int bx = blockIdx.x;                       // grid 8000 = 8 slabs x 1000
    int gw = ((bx & 7) * 1000 + (bx >> 3)) * 4 + wid;  // 0 .. 31999
    int bn = gw >> 1, hp = gw & 1;
    int hg = lane >> 4, cq = lane & 15;
    int h = hp * 4 + hg;
    int b = bn / NTOK, n = bn - b * NTOK;
    int y = n / 400;
    int r2 = n - y * 400;
    int x = r2 / 20;
    int z = r2 - x * 20;

    const float* op = offb + (size_t)bn * 96 + h * 12;
    const float* lp = lgb + (size_t)bn * 32 + h * 4;
    float l0 = lp[0], l1 = lp[1], l2 = lp[2], l3 = lp[3];
    float mx = fmaxf(fmaxf(l0, l1), fmaxf(l2, l3));
    float e0 = expf(l0 - mx), e1 = expf(l1 - mx), e2 = expf(l2 - mx), e3 = expf(l3 - mx);
    float inv = 1.f / (e0 + e1 + e2 + e3);
    float at[4] = {e0 * inv, e1 * inv, e2 * inv, e3 * inv};

    const u16* volb = vol + (size_t)b * NTOK * C_DIM + h * HDIM + cq * 4;
    float4 acc = make_float4(0.f, 0.f, 0.f, 0.f);
#pragma unroll
    for (int p = 0; p < 4; p++) {
        float o0 = fminf(fmaxf(op[p * 3 + 0], -3.f), 3.f);
        float o1 = fminf(fmaxf(op[p * 3 + 1], -3.f), 3.f);
        float o2 = fminf(fmaxf(op[p * 3 + 2], -3.f), 3.f);
        float ix = fminf(fmaxf((float)y + o0, 0.f), 19.f);  // W axis
        float iy = fminf(fmaxf((float)x + o1, 0.f), 19.f);  // H axis
        float iz = fminf(fmaxf((float)z + o2, 0.f), 19.f);  // D axis
        float xf = floorf(ix), yf = floorf(iy), zf = floorf(iz);
        float fx = ix - xf, fy = iy - yf, fz = iz - zf;
        int x0 = (int)xf, y0 = (int)yf, z0 = (int)zf;
        int x1 = imin(x0 + 1, 19), y1 = imin(y0 + 1, 19), z1 = imin(z0 + 1, 19);
        // spatial = yi*400 + xi*20 + zi, channels contiguous (stride C_DIM)
        int s00 = y0 * 400 + x0 * 20, s01 = y0 * 400 + x1 * 20;
        int s10 = y1 * 400 + x0 * 20, s11 = y1 * 400 + x1 * 20;
        uint2 v000 = *(const uint2*)(volb + (size_t)(s00 + z0) * C_DIM);
        uint2 v001 = *(const uint2*)(volb + (size_t)(s01 + z0) * C_DIM);
        uint2 v010 = *(const uint2*)(volb + (size_t)(s10 + z0) * C_DIM);
        uint2 v011 = *(const uint2*)(volb + (size_t)(s11 + z0) * C_DIM);
        uint2 v100 = *(const uint2*)(volb + (size_t)(s00 + z1) * C_DIM);
        uint2 v101 = *(const uint2*)(volb + (size_t)(s01 + z1) * C_DIM);
        uint2 v110 = *(const uint2*)(volb + (size_t)(s10 + z1) * C_DIM);
        uint2 v111 = *(const uint2*)(volb + (size_t)(s11 + z1) * C_DIM);
        float wz0 = (1.f - fz) * at[p], wz1 = fz * at[p];
        float w00 = wz0 * (1.f - fy), w01 = wz0 * fy;
        float w10 = wz1 * (1.f - fy), w11 = wz1 * fy;
        float gx0 = 1.f - fx;
        fmabf(acc, v000, w00 * gx0); fmabf(acc, v001, w00 * fx);
        fmabf(acc, v010, w01 * gx0); fmabf(acc, v011, w01 * fx);
        fmabf(acc, v100, w10 * gx0); fmabf(acc, v101, w10 * fx);
        fmabf(acc, v110, w11 * gx0); fmabf(acc, v111, w11 * fx);
    }
    ushort4 o;
    o.x = f2bf(acc.x); o.y = f2bf(acc.y); o.z = f2bf(acc.z); o.w = f2bf(acc.w);
    *reinterpret_cast<ushort4*>(outp + (size_t)bn * C_DIM + h * HDIM + cq * 4) = o;
}

// ---------------------------------------------------------------------------
// Launch
// ---------------------------------------------------------------------------
extern "C" void kernel_launch(void* const* d_in, const int* in_sizes, int n_in,
                              void* d_out, int out_size, void* d_ws, size_t ws_size,
                              hipStream_t stream)
{
    const float* f_query = (const float*)d_in[0];
    const float* f_kv    = (const float*)d_in[1];
    const float* ln_g    = (const float*)d_in[2];
    const float* ln_b    = (const float*)d_in[3];
    const float* Wq      = (const float*)d_in[4];
    const float* bq      = (const float*)d_in[5];
    const float* Wo1     = (const float*)d_in[6];
    const float* bo1     = (const float*)d_in[7];
    const float* Wo2     = (const float*)d_in[8];
    const float* bo2     = (const float*)d_in[9];
    const float* Wa      = (const float*)d_in[10];
    const float* ba      = (const float*)d_in[11];
    const float* Wout    = (const float*)d_in[12];
    const float* bout    = (const float*)d_in[13];
    float* out = (float*)d_out;

    float* ws = (float*)d_ws;
    float* offb = ws;                     // 1,536,000 f
    float* lgb  = ws + 1536000;           //   512,000 f
    u16* kvT   = (u16*)(ws + 2048000);    // 8,192,000 u16 (bf16 channels-last)
    u16* qb    = (u16*)(ws + 6144000);    // 8,192,000 u16 (q; later sampled)
    u16* Qb    = (u16*)(ws + 10240000);   // 8,192,000 u16
    u16* hid   = (u16*)(ws + 14336000);   // 8,192,000 u16
    u16* WqT   = (u16*)(ws + 18432000);   // 512x512
    u16* Wo1T  = WqT + 262144;
    u16* WoutT = Wo1T + 262144;
    u16* Wo2T  = WoutT + 262144;          // 128x512 (96 valid, pad 0)
    u16* WaT   = Wo2T + 65536;            // 128x512 (32 valid, pad 0)
    // total ~75.6 MiB

    dim3 blk(256);
    // all weight transpose-converts in one dispatch
    wcvt_all<<<dim3(16, 16, 5), blk, 0, stream>>>(
        Wq, WqT, Wo1, Wo1T, Wout, WoutT, Wo2, Wo2T, Wa, WaT);
    // f_kv (B,C,N) fp32 -> kvT (B,N,C) bf16
    transpose_c2l_bf16<<<dim3(250, 16, 2), blk, 0, stream>>>(f_kv, kvT);
    // q = LN(transpose(f_query)) -> bf16, fused LDS tile
    ln_fused<<<dim3(500), blk, 0, stream>>>(f_query, ln_g, ln_b, qb);
    // Q = q @ Wq + bq -> bf16
    gemm_bf16<<<dim3(4, 125), blk, 0, stream>>>(qb, WqT, bq, nullptr, Qb, 512, 512, 0, 1);
    // hidden = relu(Q @ Wo1 + bo1) -> bf16
    gemm_bf16<<<dim3(4, 125), blk, 0, stream>>>(Qb, Wo1T, bo1, nullptr, hid, 512, 512, 1, 1);
    // off = hidden @ Wo2 + bo2 (fp32) AND logits = Q @ Wa + ba (fp32), one dispatch
    gemm_dual<<<dim3(1, 125, 2), blk, 0, stream>>>(
        hid, Wo2T, bo2, offb, 96, Qb, WaT, ba, lgb, 32);
    // fused sample/softmax/einsum -> qb (bf16)
    sample_kernel<<<dim3(8000), blk, 0, stream>>>(kvT, offb, lgb, qb);
    // out(B,C,N) = (sampled @ Wout + bout)^T  via  WoutT @ sampled^T, mode 2
    gemm_bf16<<<dim3(125, 4), blk, 0, stream>>>(WoutT, qb, bout, out, nullptr, 16000, 0, 0, 2);
}

// Round 6
// 269.069 us; speedup vs baseline: 2.8503x; 1.0013x over previous
//
#include <hip/hip_runtime.h>
#include <math.h>

// Problem constants
#define C_DIM 512
#define NHEAD 8
#define HDIM 64
#define NTOK 8000
#define BN_TOK 16000

typedef __attribute__((ext_vector_type(8))) short bf16x8;
typedef __attribute__((ext_vector_type(4))) float f32x4;
typedef __attribute__((ext_vector_type(2))) _Float16 h2;
typedef unsigned short u16;

__device__ __forceinline__ int imin(int a, int b) { return a < b ? a : b; }

// fp32 -> bf16 round-to-nearest-even
__device__ __forceinline__ u16 f2bf(float x) {
    union { float f; unsigned u; } c; c.f = x;
    unsigned r = c.u + 0x7FFFu + ((c.u >> 16) & 1u);
    return (u16)(r >> 16);
}

// fp32 -> f16 (RNE)
__device__ __forceinline__ u16 f2h(float x) {
    _Float16 h = (_Float16)x;
    return __builtin_bit_cast(u16, h);
}

// async global->LDS, 16 bytes per lane (global_load_lds_dwordx4)
__device__ __forceinline__ void async16(const void* g, void* l) {
    __builtin_amdgcn_global_load_lds(
        (const __attribute__((address_space(1))) void*)g,
        (__attribute__((address_space(3))) void*)l, 16, 0, 0);
}

// fma of 8 f16 channels (one uint4) into fp32 acc — v_fma_mix_f32 path
__device__ __forceinline__ void fmah(float* a, const uint4& d, float w) {
    h2 v0 = __builtin_bit_cast(h2, d.x);
    h2 v1 = __builtin_bit_cast(h2, d.y);
    h2 v2 = __builtin_bit_cast(h2, d.z);
    h2 v3 = __builtin_bit_cast(h2, d.w);
    a[0] = fmaf((float)v0.x, w, a[0]);
    a[1] = fmaf((float)v0.y, w, a[1]);
    a[2] = fmaf((float)v1.x, w, a[2]);
    a[3] = fmaf((float)v1.y, w, a[3]);
    a[4] = fmaf((float)v2.x, w, a[4]);
    a[5] = fmaf((float)v2.y, w, a[5]);
    a[6] = fmaf((float)v3.x, w, a[6]);
    a[7] = fmaf((float)v3.y, w, a[7]);
}

// ---------------------------------------------------------------------------
// f_kv (B,C,N) fp32 -> kvT (B,N,C) f16. Fixed 512 x 8000 per batch.
// ---------------------------------------------------------------------------
__global__ __launch_bounds__(256) void transpose_c2l_f16(
    const float* __restrict__ in, u16* __restrict__ out)
{
    __shared__ float tile[32][33];
    int b = blockIdx.z;
    const float* inb = in + (size_t)b * 512 * NTOK;
    u16* outb = out + (size_t)b * NTOK * 512;
    int s0 = blockIdx.x * 32, r0 = blockIdx.y * 32;   // s: token, r: channel
    int tx = threadIdx.x & 31, ty = threadIdx.x >> 5;
#pragma unroll
    for (int i = 0; i < 4; i++)
        tile[ty + i * 8][tx] = inb[(size_t)(r0 + ty + i * 8) * NTOK + s0 + tx];
    __syncthreads();
    int rq = threadIdx.x & 7, sy = threadIdx.x >> 3;  // rq: channel quad, sy: token
    ushort4 o;
    o.x = f2h(tile[rq * 4 + 0][sy]);
    o.y = f2h(tile[rq * 4 + 1][sy]);
    o.z = f2h(tile[rq * 4 + 2][sy]);
    o.w = f2h(tile[rq * 4 + 3][sy]);
    *reinterpret_cast<ushort4*>(outb + (size_t)(s0 + sy) * 512 + r0 + rq * 4) = o;
}

// ---------------------------------------------------------------------------
// Merged weight converts: z selects which W (512 x Nout) fp32 -> (Npad x 512)
// bf16, pad rows zeroed. Grid (16,16,5); small weights early-out on x.
// ---------------------------------------------------------------------------
__global__ __launch_bounds__(256) void wcvt_all(
    const float* __restrict__ W0, u16* __restrict__ T0,
    const float* __restrict__ W1, u16* __restrict__ T1,
    const float* __restrict__ W2, u16* __restrict__ T2,
    const float* __restrict__ W3, u16* __restrict__ T3,
    const float* __restrict__ W4, u16* __restrict__ T4)
{
    const float* W; u16* Wt; int Nout, Npad;
    switch (blockIdx.z) {
        case 0: W = W0; Wt = T0; Nout = 512; Npad = 512; break;
        case 1: W = W1; Wt = T1; Nout = 512; Npad = 512; break;
        case 2: W = W2; Wt = T2; Nout = 512; Npad = 512; break;
        case 3: W = W3; Wt = T3; Nout = 96;  Npad = 128; break;
        default: W = W4; Wt = T4; Nout = 32; Npad = 128; break;
    }
    int n0 = blockIdx.x * 32, k0 = blockIdx.y * 32;
    if (n0 >= Npad) return;
    __shared__ float t[32][33];
    int tx = threadIdx.x & 31, ty = threadIdx.x >> 5;
#pragma unroll
    for (int i = 0; i < 4; i++) {
        int k = k0 + ty + i * 8, n = n0 + tx;
        t[ty + i * 8][tx] = (n < Nout) ? W[(size_t)k * Nout + n] : 0.f;
    }
    __syncthreads();
#pragma unroll
    for (int i = 0; i < 4; i++) {
        int n = n0 + ty + i * 8, k = k0 + tx;
        Wt[(size_t)n * 512 + k] = f2bf(t[tx][ty + i * 8]);
    }
}

// ---------------------------------------------------------------------------
// Fused LayerNorm + (B,C,N)->(B,N,C) transpose, LDS-tiled for ideal fetch.
// ---------------------------------------------------------------------------
__global__ __launch_bounds__(256) void ln_fused(
    const float* __restrict__ fq, const float* __restrict__ gamma,
    const float* __restrict__ beta, u16* __restrict__ q)
{
    __shared__ float tile[512][33];   // [c][t], 67.6 KB
    __shared__ float ps[32][17], pq[32][17];
    __shared__ float muA[32], rsA[32];
    int blk = blockIdx.x;
    int b = blk / 250;
    int n0 = (blk - b * 250) * 32;
    const float* src = fq + (size_t)b * C_DIM * NTOK + n0;
    int tid = threadIdx.x;
    int cgrp = tid >> 4;          // 0..15
    int tp = (tid & 15) * 2;      // 0,2,..,30
    float s0 = 0.f, q0 = 0.f, s1 = 0.f, q1 = 0.f;
#pragma unroll 4
    for (int it = 0; it < 32; ++it) {
        int c = it * 16 + cgrp;
        float2 v = *reinterpret_cast<const float2*>(src + (size_t)c * NTOK + tp);
        tile[c][tp] = v.x; tile[c][tp + 1] = v.y;
        s0 += v.x; q0 += v.x * v.x;
        s1 += v.y; q1 += v.y * v.y;
    }
    ps[tp][cgrp] = s0; pq[tp][cgrp] = q0;
    ps[tp + 1][cgrp] = s1; pq[tp + 1][cgrp] = q1;
    int lane = tid & 63, wv = tid >> 6;
    float4 g0 = *reinterpret_cast<const float4*>(gamma + lane * 4);
    float4 be0 = *reinterpret_cast<const float4*>(beta + lane * 4);
    float4 g1 = *reinterpret_cast<const float4*>(gamma + 256 + lane * 4);
    float4 be1 = *reinterpret_cast<const float4*>(beta + 256 + lane * 4);
    __syncthreads();
    if (tid < 32) {
        float S = 0.f, SQ = 0.f;
#pragma unroll
        for (int g = 0; g < 16; ++g) { S += ps[tid][g]; SQ += pq[tid][g]; }
        float mu = S * (1.f / 512.f);
        float var = SQ * (1.f / 512.f) - mu * mu;
        muA[tid] = mu;
        rsA[tid] = rsqrtf(var + 1e-5f);
    }
    __syncthreads();
#pragma unroll
    for (int it = 0; it < 16; ++it) {
        int task = it * 4 + wv;     // 0..63 : (token, half)
        int t = task >> 1, h = task & 1;
        int c0 = h * 256 + lane * 4;
        float mu = muA[t], rs = rsA[t];
        float4 g = h ? g1 : g0, bb = h ? be1 : be0;
        ushort4 o;
        o.x = f2bf((tile[c0 + 0][t] - mu) * rs * g.x + bb.x);
        o.y = f2bf((tile[c0 + 1][t] - mu) * rs * g.y + bb.y);
        o.z = f2bf((tile[c0 + 2][t] - mu) * rs * g.z + bb.z);
        o.w = f2bf((tile[c0 + 3][t] - mu) * rs * g.w + bb.w);
        *reinterpret_cast<ushort4*>(q + ((size_t)(b * NTOK + n0 + t)) * C_DIM + c0) = o;
    }
}

// ---------------------------------------------------------------------------
// bf16 MFMA GEMM body, BK=64: C[M,Nout] = A[M,512] @ Bt[.,512]^T.
// 128x128 tile, 8 K-iterations (half the barrier drains of BK=32), 32 KB LDS.
// XOR swizzle over 8 segments: LDS slot s holds global seg s^(row&7);
// fragment reads hit each 16B window with 2 lanes (2-way = free, m136).
// mode 0: fp32 row-major (ldc), bias[col]
// mode 1: bf16 row-major (ldc), bias[col]
// mode 2: fp32 direct (B,C,N) store — rows=channels, cols=tokens; bias[row].
// ---------------------------------------------------------------------------
__device__ __forceinline__ void gemm_body(
    const u16* __restrict__ A, const u16* __restrict__ Bt,
    const float* __restrict__ bias, float* __restrict__ Cf,
    u16* __restrict__ Cb, int Nout, int ldc, int relu, int mode,
    int bx, int by)
{
    __shared__ u16 As[128 * 64];  // 16 KB
    __shared__ u16 Bs[128 * 64];
    int tid = threadIdx.x, lane = tid & 63, wv = tid >> 6;
    int bm = by * 128, bn = bx * 128;
    int wm = (wv >> 1) * 64, wn = (wv & 1) * 64;

    f32x4 acc[4][4];
#pragma unroll
    for (int i = 0; i < 4; i++)
#pragma unroll
        for (int j = 0; j < 4; j++) acc[i][j] = (f32x4){0.f, 0.f, 0.f, 0.f};

    // staging: 1024 16B-segments per tile, 4 chunks/thread
    int rS[4], sS[4], dS[4];
#pragma unroll
    for (int c = 0; c < 4; c++) {
        int lin = (c * 4 + wv) * 64 + lane;
        rS[c] = lin >> 3;
        sS[c] = (lin & 7) ^ (rS[c] & 7);
        dS[c] = lin * 8;   // u16 units
    }

    const u16* Ab = A + (size_t)bm * 512;
    const u16* Bb = Bt + (size_t)bn * 512;

    int ml = lane & 15, quad = lane >> 4;
    int offA[4][2], offB[4][2];
#pragma unroll
    for (int i = 0; i < 4; i++) {
        int r = wm + i * 16 + ml;
        int rb = wn + i * 16 + ml;
#pragma unroll
        for (int kk = 0; kk < 2; kk++) {
            offA[i][kk] = r * 64 + (((kk * 4 + quad) ^ (r & 7)) * 8);
            offB[i][kk] = rb * 64 + (((kk * 4 + quad) ^ (rb & 7)) * 8);
        }
    }

    for (int k0 = 0; k0 < 512; k0 += 64) {
#pragma unroll
        for (int c = 0; c < 4; c++) {
            async16(Ab + (size_t)rS[c] * 512 + k0 + sS[c] * 8, As + dS[c]);
            async16(Bb + (size_t)rS[c] * 512 + k0 + sS[c] * 8, Bs + dS[c]);
        }
        __syncthreads();
#pragma unroll
        for (int kk = 0; kk < 2; kk++) {
            bf16x8 af[4], bfr[4];
#pragma unroll
            for (int i = 0; i < 4; i++) {
                af[i]  = *reinterpret_cast<const bf16x8*>(As + offA[i][kk]);
                bfr[i] = *reinterpret_cast<const bf16x8*>(Bs + offB[i][kk]);
            }
#pragma unroll
            for (int i = 0; i < 4; i++)
#pragma unroll
                for (int j = 0; j < 4; j++)
                    acc[i][j] = __builtin_amdgcn_mfma_f32_16x16x32_bf16(
                        af[i], bfr[j], acc[i][j], 0, 0, 0);
        }
        __syncthreads();
    }

    // epilogue: C/D layout col=lane&15, row=quad*4+reg (m89/m91 verified)
#pragma unroll
    for (int i = 0; i < 4; i++) {
        int row = bm + wm + i * 16 + quad * 4;
#pragma unroll
        for (int j = 0; j < 4; j++) {
            int col = bn + wn + j * 16 + ml;
            if (col < Nout) {
                float bia = (mode == 2) ? 0.f : bias[col];
#pragma unroll
                for (int rg = 0; rg < 4; rg++) {
                    float v = acc[i][j][rg] + ((mode == 2) ? bias[row + rg] : bia);
                    if (relu) v = fmaxf(v, 0.f);
                    if (mode == 2) {
                        int bb = col >= 8000;
                        int nn = col - bb * 8000;
                        Cf[((size_t)(bb * 512 + row + rg)) * 8000 + nn] = v;
                    } else {
                        size_t idx = (size_t)(row + rg) * ldc + col;
                        if (mode == 1) Cb[idx] = f2bf(v);
                        else           Cf[idx] = v;
                    }
                }
            }
        }
    }
}

__global__ __launch_bounds__(256) void gemm_bf16(
    const u16* __restrict__ A, const u16* __restrict__ Bt,
    const float* __restrict__ bias, float* __restrict__ Cf,
    u16* __restrict__ Cb, int Nout, int ldc, int relu, int mode)
{
    gemm_body(A, Bt, bias, Cf, Cb, Nout, ldc, relu, mode,
              blockIdx.x, blockIdx.y);
}

// Two independent small GEMMs in one dispatch (z selects operand set).
__global__ __launch_bounds__(256) void gemm_dual(
    const u16* __restrict__ A0, const u16* __restrict__ B0,
    const float* __restrict__ bias0, float* __restrict__ C0, int N0,
    const u16* __restrict__ A1, const u16* __restrict__ B1,
    const float* __restrict__ bias1, float* __restrict__ C1, int N1)
{
    if (blockIdx.z == 0)
        gemm_body(A0, B0, bias0, C0, nullptr, N0, N0, 0, 0, blockIdx.x, blockIdx.y);
    else
        gemm_body(A1, B1, bias1, C1, nullptr, N1, N1, 0, 0, blockIdx.x, blockIdx.y);
}

// ---------------------------------------------------------------------------
// Fused softmax + offset clip + trilinear sample + einsum, f16 volume.
// One wave = one token (all 8 heads); lane = h*8 + cl, 8 channels/lane via
// one uint4 (8 x f16) corner load. Per-head scalar math replicated over only
// 8 lanes; f16->f32 via v_fma_mix (1 VALU/channel). attn folded into corner
// weights. XCD swizzle: blockIdx.x & 7 -> 2000-token contiguous slab per XCD.
// Reference quirk: off-ch0 -> W(x) axis, ch1 -> H(y), ch2 -> D(z); H=W=D=20
// collapses normalization to clip(base+off, 0, 19).
// ---------------------------------------------------------------------------
__global__ __launch_bounds__(256) void sample_kernel(
    const u16* __restrict__ vol, const float* __restrict__ offb,
    const float* __restrict__ lgb, u16* __restrict__ outp)
{
    int wid = threadIdx.x >> 6, lane = threadIdx.x & 63;
    int bx = blockIdx.x;                               // 4000 = 8 slabs x 500
    int bn = ((bx & 7) * 500 + (bx >> 3)) * 4 + wid;   // token 0..15999
    int h = lane >> 3, cl = lane & 7;
    int b = bn / NTOK, n = bn - b * NTOK;
    int y = n / 400;
    int r2 = n - y * 400;
    int x = r2 / 20;
    int z = r2 - x * 20;

    const float* op = offb + (size_t)bn * 96 + h * 12;
    const float* lp = lgb + (size_t)bn * 32 + h * 4;
    float l0 = lp[0], l1 = lp[1], l2 = lp[2], l3 = lp[3];
    float mx = fmaxf(fmaxf(l0, l1), fmaxf(l2, l3));
    float e0 = expf(l0 - mx), e1 = expf(l1 - mx), e2 = expf(l2 - mx), e3 = expf(l3 - mx);
    float inv = 1.f / (e0 + e1 + e2 + e3);
    float at[4] = {e0 * inv, e1 * inv, e2 * inv, e3 * inv};

    const u16* volb = vol + (size_t)b * NTOK * C_DIM + h * HDIM + cl * 8;
    float acc[8] = {};
#pragma unroll
    for (int p = 0; p < 4; p++) {
        float o0 = fminf(fmaxf(op[p * 3 + 0], -3.f), 3.f);
        float o1 = fminf(fmaxf(op[p * 3 + 1], -3.f), 3.f);
        float o2 = fminf(fmaxf(op[p * 3 + 2], -3.f), 3.f);
        float ix = fminf(fmaxf((float)y + o0, 0.f), 19.f);  // W axis
        float iy = fminf(fmaxf((float)x + o1, 0.f), 19.f);  // H axis
        float iz = fminf(fmaxf((float)z + o2, 0.f), 19.f);  // D axis
        float xf = floorf(ix), yf = floorf(iy), zf = floorf(iz);
        float fx = ix - xf, fy = iy - yf, fz = iz - zf;
        int x0 = (int)xf, y0 = (int)yf, z0 = (int)zf;
        int x1 = imin(x0 + 1, 19), y1 = imin(y0 + 1, 19), z1 = imin(z0 + 1, 19);
        // spatial = yi*400 + xi*20 + zi, channels contiguous (stride C_DIM)
        int s00 = y0 * 400 + x0 * 20, s01 = y0 * 400 + x1 * 20;
        int s10 = y1 * 400 + x0 * 20, s11 = y1 * 400 + x1 * 20;
        uint4 v000 = *(const uint4*)(volb + (size_t)(s00 + z0) * C_DIM);
        uint4 v001 = *(const uint4*)(volb + (size_t)(s01 + z0) * C_DIM);
        uint4 v010 = *(const uint4*)(volb + (size_t)(s10 + z0) * C_DIM);
        uint4 v011 = *(const uint4*)(volb + (size_t)(s11 + z0) * C_DIM);
        uint4 v100 = *(const uint4*)(volb + (size_t)(s00 + z1) * C_DIM);
        uint4 v101 = *(const uint4*)(volb + (size_t)(s01 + z1) * C_DIM);
        uint4 v110 = *(const uint4*)(volb + (size_t)(s10 + z1) * C_DIM);
        uint4 v111 = *(const uint4*)(volb + (size_t)(s11 + z1) * C_DIM);
        float wz0 = (1.f - fz) * at[p], wz1 = fz * at[p];
        float w00 = wz0 * (1.f - fy), w01 = wz0 * fy;
        float w10 = wz1 * (1.f - fy), w11 = wz1 * fy;
        float gx0 = 1.f - fx;
        fmah(acc, v000, w00 * gx0); fmah(acc, v001, w00 * fx);
        fmah(acc, v010, w01 * gx0); fmah(acc, v011, w01 * fx);
        fmah(acc, v100, w10 * gx0); fmah(acc, v101, w10 * fx);
        fmah(acc, v110, w11 * gx0); fmah(acc, v111, w11 * fx);
    }
    u16 ov[8];
#pragma unroll
    for (int c = 0; c < 8; c++) ov[c] = f2bf(acc[c]);
    *reinterpret_cast<uint4*>(outp + (size_t)bn * C_DIM + h * HDIM + cl * 8) =
        *reinterpret_cast<uint4*>(ov);
}

// ---------------------------------------------------------------------------
// Launch
// ---------------------------------------------------------------------------
extern "C" void kernel_launch(void* const* d_in, const int* in_sizes, int n_in,
                              void* d_out, int out_size, void* d_ws, size_t ws_size,
                              hipStream_t stream)
{
    const float* f_query = (const float*)d_in[0];
    const float* f_kv    = (const float*)d_in[1];
    const float* ln_g    = (const float*)d_in[2];
    const float* ln_b    = (const float*)d_in[3];
    const float* Wq      = (const float*)d_in[4];
    const float* bq      = (const float*)d_in[5];
    const float* Wo1     = (const float*)d_in[6];
    const float* bo1     = (const float*)d_in[7];
    const float* Wo2     = (const float*)d_in[8];
    const float* bo2     = (const float*)d_in[9];
    const float* Wa      = (const float*)d_in[10];
    const float* ba      = (const float*)d_in[11];
    const float* Wout    = (const float*)d_in[12];
    const float* bout    = (const float*)d_in[13];
    float* out = (float*)d_out;

    float* ws = (float*)d_ws;
    float* offb = ws;                     // 1,536,000 f
    float* lgb  = ws + 1536000;           //   512,000 f
    u16* kvT   = (u16*)(ws + 2048000);    // 8,192,000 u16 (f16 channels-last)
    u16* qb    = (u16*)(ws + 6144000);    // 8,192,000 u16 (q; later sampled)
    u16* Qb    = (u16*)(ws + 10240000);   // 8,192,000 u16
    u16* hid   = (u16*)(ws + 14336000);   // 8,192,000 u16
    u16* WqT   = (u16*)(ws + 18432000);   // 512x512
    u16* Wo1T  = WqT + 262144;
    u16* WoutT = Wo1T + 262144;
    u16* Wo2T  = WoutT + 262144;          // 128x512 (96 valid, pad 0)
    u16* WaT   = Wo2T + 65536;            // 128x512 (32 valid, pad 0)
    // total ~75.6 MiB

    dim3 blk(256);
    // all weight transpose-converts in one dispatch
    wcvt_all<<<dim3(16, 16, 5), blk, 0, stream>>>(
        Wq, WqT, Wo1, Wo1T, Wout, WoutT, Wo2, Wo2T, Wa, WaT);
    // f_kv (B,C,N) fp32 -> kvT (B,N,C) f16
    transpose_c2l_f16<<<dim3(250, 16, 2), blk, 0, stream>>>(f_kv, kvT);
    // q = LN(transpose(f_query)) -> bf16, fused LDS tile
    ln_fused<<<dim3(500), blk, 0, stream>>>(f_query, ln_g, ln_b, qb);
    // Q = q @ Wq + bq -> bf16
    gemm_bf16<<<dim3(4, 125), blk, 0, stream>>>(qb, WqT, bq, nullptr, Qb, 512, 512, 0, 1);
    // hidden = relu(Q @ Wo1 + bo1) -> bf16
    gemm_bf16<<<dim3(4, 125), blk, 0, stream>>>(Qb, Wo1T, bo1, nullptr, hid, 512, 512, 1, 1);
    // off = hidden @ Wo2 + bo2 (fp32) AND logits = Q @ Wa + ba (fp32), one dispatch
    gemm_dual<<<dim3(1, 125, 2), blk, 0, stream>>>(
        hid, Wo2T, bo2, offb, 96, Qb, WaT, ba, lgb, 32);
    // fused sample/softmax/einsum -> qb (bf16)
    sample_kernel<<<dim3(4000), blk, 0, stream>>>(kvT, offb, lgb, qb);
    // out(B,C,N) = (sampled @ Wout + bout)^T  via  WoutT @ sampled^T, mode 2
    gemm_bf16<<<dim3(125, 4), blk, 0, stream>>>(WoutT, qb, bout, out, nullptr, 16000, 0, 0, 2);
}

// Round 7
// 250.741 us; speedup vs baseline: 3.0587x; 1.0731x over previous
//
#include <hip/hip_runtime.h>
#include <math.h>

// Problem constants
#define C_DIM 512
#define NHEAD 8
#define HDIM 64
#define NTOK 8000
#define BN_TOK 16000

typedef __attribute__((ext_vector_type(8))) short bf16x8;
typedef __attribute__((ext_vector_type(4))) float f32x4;
typedef __attribute__((ext_vector_type(2))) _Float16 h2;
typedef unsigned short u16;

__device__ __forceinline__ int imin(int a, int b) { return a < b ? a : b; }

// fp32 -> bf16 round-to-nearest-even
__device__ __forceinline__ u16 f2bf(float x) {
    union { float f; unsigned u; } c; c.f = x;
    unsigned r = c.u + 0x7FFFu + ((c.u >> 16) & 1u);
    return (u16)(r >> 16);
}

// fp32 -> f16 (RNE)
__device__ __forceinline__ u16 f2h(float x) {
    _Float16 h = (_Float16)x;
    return __builtin_bit_cast(u16, h);
}

// async global->LDS, 16 bytes per lane (global_load_lds_dwordx4)
__device__ __forceinline__ void async16(const void* g, void* l) {
    __builtin_amdgcn_global_load_lds(
        (const __attribute__((address_space(1))) void*)g,
        (__attribute__((address_space(3))) void*)l, 16, 0, 0);
}

// fma of 8 f16 channels (one uint4) into fp32 acc — v_fma_mix_f32 path
__device__ __forceinline__ void fmah(float* a, const uint4& d, float w) {
    h2 v0 = __builtin_bit_cast(h2, d.x);
    h2 v1 = __builtin_bit_cast(h2, d.y);
    h2 v2 = __builtin_bit_cast(h2, d.z);
    h2 v3 = __builtin_bit_cast(h2, d.w);
    a[0] = fmaf((float)v0.x, w, a[0]);
    a[1] = fmaf((float)v0.y, w, a[1]);
    a[2] = fmaf((float)v1.x, w, a[2]);
    a[3] = fmaf((float)v1.y, w, a[3]);
    a[4] = fmaf((float)v2.x, w, a[4]);
    a[5] = fmaf((float)v2.y, w, a[5]);
    a[6] = fmaf((float)v3.x, w, a[6]);
    a[7] = fmaf((float)v3.y, w, a[7]);
}

// ---------------------------------------------------------------------------
// f_kv (B,C,N) fp32 -> kvT (B,N,C) f16. Fixed 512 x 8000 per batch.
// ---------------------------------------------------------------------------
__global__ __launch_bounds__(256) void transpose_c2l_f16(
    const float* __restrict__ in, u16* __restrict__ out)
{
    __shared__ float tile[32][33];
    int b = blockIdx.z;
    const float* inb = in + (size_t)b * 512 * NTOK;
    u16* outb = out + (size_t)b * NTOK * 512;
    int s0 = blockIdx.x * 32, r0 = blockIdx.y * 32;   // s: token, r: channel
    int tx = threadIdx.x & 31, ty = threadIdx.x >> 5;
#pragma unroll
    for (int i = 0; i < 4; i++)
        tile[ty + i * 8][tx] = inb[(size_t)(r0 + ty + i * 8) * NTOK + s0 + tx];
    __syncthreads();
    int rq = threadIdx.x & 7, sy = threadIdx.x >> 3;  // rq: channel quad, sy: token
    ushort4 o;
    o.x = f2h(tile[rq * 4 + 0][sy]);
    o.y = f2h(tile[rq * 4 + 1][sy]);
    o.z = f2h(tile[rq * 4 + 2][sy]);
    o.w = f2h(tile[rq * 4 + 3][sy]);
    *reinterpret_cast<ushort4*>(outb + (size_t)(s0 + sy) * 512 + r0 + rq * 4) = o;
}

// ---------------------------------------------------------------------------
// Merged weight converts: z selects which W (512 x Nout) fp32 -> (Npad x 512)
// bf16, pad rows zeroed. Grid (16,16,5); small weights early-out on x.
// ---------------------------------------------------------------------------
__global__ __launch_bounds__(256) void wcvt_all(
    const float* __restrict__ W0, u16* __restrict__ T0,
    const float* __restrict__ W1, u16* __restrict__ T1,
    const float* __restrict__ W2, u16* __restrict__ T2,
    const float* __restrict__ W3, u16* __restrict__ T3,
    const float* __restrict__ W4, u16* __restrict__ T4)
{
    const float* W; u16* Wt; int Nout, Npad;
    switch (blockIdx.z) {
        case 0: W = W0; Wt = T0; Nout = 512; Npad = 512; break;
        case 1: W = W1; Wt = T1; Nout = 512; Npad = 512; break;
        case 2: W = W2; Wt = T2; Nout = 512; Npad = 512; break;
        case 3: W = W3; Wt = T3; Nout = 96;  Npad = 128; break;
        default: W = W4; Wt = T4; Nout = 32; Npad = 128; break;
    }
    int n0 = blockIdx.x * 32, k0 = blockIdx.y * 32;
    if (n0 >= Npad) return;
    __shared__ float t[32][33];
    int tx = threadIdx.x & 31, ty = threadIdx.x >> 5;
#pragma unroll
    for (int i = 0; i < 4; i++) {
        int k = k0 + ty + i * 8, n = n0 + tx;
        t[ty + i * 8][tx] = (n < Nout) ? W[(size_t)k * Nout + n] : 0.f;
    }
    __syncthreads();
#pragma unroll
    for (int i = 0; i < 4; i++) {
        int n = n0 + ty + i * 8, k = k0 + tx;
        Wt[(size_t)n * 512 + k] = f2bf(t[tx][ty + i * 8]);
    }
}

// ---------------------------------------------------------------------------
// Fused LayerNorm + (B,C,N)->(B,N,C) transpose, LDS-tiled for ideal fetch.
// ---------------------------------------------------------------------------
__global__ __launch_bounds__(256) void ln_fused(
    const float* __restrict__ fq, const float* __restrict__ gamma,
    const float* __restrict__ beta, u16* __restrict__ q)
{
    __shared__ float tile[512][33];   // [c][t], 67.6 KB
    __shared__ float ps[32][17], pq[32][17];
    __shared__ float muA[32], rsA[32];
    int blk = blockIdx.x;
    int b = blk / 250;
    int n0 = (blk - b * 250) * 32;
    const float* src = fq + (size_t)b * C_DIM * NTOK + n0;
    int tid = threadIdx.x;
    int cgrp = tid >> 4;          // 0..15
    int tp = (tid & 15) * 2;      // 0,2,..,30
    float s0 = 0.f, q0 = 0.f, s1 = 0.f, q1 = 0.f;
#pragma unroll 4
    for (int it = 0; it < 32; ++it) {
        int c = it * 16 + cgrp;
        float2 v = *reinterpret_cast<const float2*>(src + (size_t)c * NTOK + tp);
        tile[c][tp] = v.x; tile[c][tp + 1] = v.y;
        s0 += v.x; q0 += v.x * v.x;
        s1 += v.y; q1 += v.y * v.y;
    }
    ps[tp][cgrp] = s0; pq[tp][cgrp] = q0;
    ps[tp + 1][cgrp] = s1; pq[tp + 1][cgrp] = q1;
    int lane = tid & 63, wv = tid >> 6;
    float4 g0 = *reinterpret_cast<const float4*>(gamma + lane * 4);
    float4 be0 = *reinterpret_cast<const float4*>(beta + lane * 4);
    float4 g1 = *reinterpret_cast<const float4*>(gamma + 256 + lane * 4);
    float4 be1 = *reinterpret_cast<const float4*>(beta + 256 + lane * 4);
    __syncthreads();
    if (tid < 32) {
        float S = 0.f, SQ = 0.f;
#pragma unroll
        for (int g = 0; g < 16; ++g) { S += ps[tid][g]; SQ += pq[tid][g]; }
        float mu = S * (1.f / 512.f);
        float var = SQ * (1.f / 512.f) - mu * mu;
        muA[tid] = mu;
        rsA[tid] = rsqrtf(var + 1e-5f);
    }
    __syncthreads();
#pragma unroll
    for (int it = 0; it < 16; ++it) {
        int task = it * 4 + wv;     // 0..63 : (token, half)
        int t = task >> 1, h = task & 1;
        int c0 = h * 256 + lane * 4;
        float mu = muA[t], rs = rsA[t];
        float4 g = h ? g1 : g0, bb = h ? be1 : be0;
        ushort4 o;
        o.x = f2bf((tile[c0 + 0][t] - mu) * rs * g.x + bb.x);
        o.y = f2bf((tile[c0 + 1][t] - mu) * rs * g.y + bb.y);
        o.z = f2bf((tile[c0 + 2][t] - mu) * rs * g.z + bb.z);
        o.w = f2bf((tile[c0 + 3][t] - mu) * rs * g.w + bb.w);
        *reinterpret_cast<ushort4*>(q + ((size_t)(b * NTOK + n0 + t)) * C_DIM + c0) = o;
    }
}

// ---------------------------------------------------------------------------
// bf16 MFMA GEMM body, BK=64: C[M,Nout] = A[M,512] @ Bt[.,512]^T.
// 128x128 tile, 8 K-iterations, 32 KB LDS, XOR swizzle (2-way = free, m136).
// mode 0: fp32 row-major (ldc), bias[col]
// mode 1: bf16 row-major (ldc), bias[col]
// mode 2: fp32 direct (B,C,N) store — rows=channels, cols=tokens; bias[row].
// ---------------------------------------------------------------------------
__device__ __forceinline__ void gemm_body(
    const u16* __restrict__ A, const u16* __restrict__ Bt,
    const float* __restrict__ bias, float* __restrict__ Cf,
    u16* __restrict__ Cb, int Nout, int ldc, int relu, int mode,
    int bx, int by)
{
    __shared__ u16 As[128 * 64];  // 16 KB
    __shared__ u16 Bs[128 * 64];
    int tid = threadIdx.x, lane = tid & 63, wv = tid >> 6;
    int bm = by * 128, bn = bx * 128;
    int wm = (wv >> 1) * 64, wn = (wv & 1) * 64;

    f32x4 acc[4][4];
#pragma unroll
    for (int i = 0; i < 4; i++)
#pragma unroll
        for (int j = 0; j < 4; j++) acc[i][j] = (f32x4){0.f, 0.f, 0.f, 0.f};

    int rS[4], sS[4], dS[4];
#pragma unroll
    for (int c = 0; c < 4; c++) {
        int lin = (c * 4 + wv) * 64 + lane;
        rS[c] = lin >> 3;
        sS[c] = (lin & 7) ^ (rS[c] & 7);
        dS[c] = lin * 8;   // u16 units
    }

    const u16* Ab = A + (size_t)bm * 512;
    const u16* Bb = Bt + (size_t)bn * 512;

    int ml = lane & 15, quad = lane >> 4;
    int offA[4][2], offB[4][2];
#pragma unroll
    for (int i = 0; i < 4; i++) {
        int r = wm + i * 16 + ml;
        int rb = wn + i * 16 + ml;
#pragma unroll
        for (int kk = 0; kk < 2; kk++) {
            offA[i][kk] = r * 64 + (((kk * 4 + quad) ^ (r & 7)) * 8);
            offB[i][kk] = rb * 64 + (((kk * 4 + quad) ^ (rb & 7)) * 8);
        }
    }

    for (int k0 = 0; k0 < 512; k0 += 64) {
#pragma unroll
        for (int c = 0; c < 4; c++) {
            async16(Ab + (size_t)rS[c] * 512 + k0 + sS[c] * 8, As + dS[c]);
            async16(Bb + (size_t)rS[c] * 512 + k0 + sS[c] * 8, Bs + dS[c]);
        }
        __syncthreads();
#pragma unroll
        for (int kk = 0; kk < 2; kk++) {
            bf16x8 af[4], bfr[4];
#pragma unroll
            for (int i = 0; i < 4; i++) {
                af[i]  = *reinterpret_cast<const bf16x8*>(As + offA[i][kk]);
                bfr[i] = *reinterpret_cast<const bf16x8*>(Bs + offB[i][kk]);
            }
#pragma unroll
            for (int i = 0; i < 4; i++)
#pragma unroll
                for (int j = 0; j < 4; j++)
                    acc[i][j] = __builtin_amdgcn_mfma_f32_16x16x32_bf16(
                        af[i], bfr[j], acc[i][j], 0, 0, 0);
        }
        __syncthreads();
    }

    // epilogue: C/D layout col=lane&15, row=quad*4+reg (m89/m91 verified)
#pragma unroll
    for (int i = 0; i < 4; i++) {
        int row = bm + wm + i * 16 + quad * 4;
#pragma unroll
        for (int j = 0; j < 4; j++) {
            int col = bn + wn + j * 16 + ml;
            if (col < Nout) {
                float bia = (mode == 2) ? 0.f : bias[col];
#pragma unroll
                for (int rg = 0; rg < 4; rg++) {
                    float v = acc[i][j][rg] + ((mode == 2) ? bias[row + rg] : bia);
                    if (relu) v = fmaxf(v, 0.f);
                    if (mode == 2) {
                        int bb = col >= 8000;
                        int nn = col - bb * 8000;
                        Cf[((size_t)(bb * 512 + row + rg)) * 8000 + nn] = v;
                    } else {
                        size_t idx = (size_t)(row + rg) * ldc + col;
                        if (mode == 1) Cb[idx] = f2bf(v);
                        else           Cf[idx] = v;
                    }
                }
            }
        }
    }
}

__global__ __launch_bounds__(256) void gemm_bf16(
    const u16* __restrict__ A, const u16* __restrict__ Bt,
    const float* __restrict__ bias, float* __restrict__ Cf,
    u16* __restrict__ Cb, int Nout, int ldc, int relu, int mode)
{
    gemm_body(A, Bt, bias, Cf, Cb, Nout, ldc, relu, mode,
              blockIdx.x, blockIdx.y);
}

// Two independent small GEMMs in one dispatch (z selects operand set).
__global__ __launch_bounds__(256) void gemm_dual(
    const u16* __restrict__ A0, const u16* __restrict__ B0,
    const float* __restrict__ bias0, float* __restrict__ C0, int N0,
    const u16* __restrict__ A1, const u16* __restrict__ B1,
    const float* __restrict__ bias1, float* __restrict__ C1, int N1)
{
    if (blockIdx.z == 0)
        gemm_body(A0, B0, bias0, C0, nullptr, N0, N0, 0, 0, blockIdx.x, blockIdx.y);
    else
        gemm_body(A1, B1, bias1, C1, nullptr, N1, N1, 0, 0, blockIdx.x, blockIdx.y);
}

// ---------------------------------------------------------------------------
// Fused softmax + offset clip + trilinear sample + einsum, f16 volume.
// One wave = one token (8 heads); lane = h*8 + cl, 8 channels/lane via one
// uint4 (8 x f16) corner load, f16->f32 via v_fma_mix. attn folded into
// corner weights. The p-loop is NOT unrolled (pragma unroll 1): only one
// point's 8 corner loads (32 VGPRs) live at a time — R6's full unroll hit
// 132 VGPR -> 9% occupancy -> latency-bound. 32-bit element offsets (volume
// is 8.2 MB) avoid v_mad_u64 address chains.
// XCD swizzle: blockIdx.x & 7 -> 2000-token contiguous slab per XCD.
// Reference quirk: off-ch0 -> W(x) axis, ch1 -> H(y), ch2 -> D(z); H=W=D=20
// collapses normalization to clip(base+off, 0, 19).
// ---------------------------------------------------------------------------
__global__ __launch_bounds__(256) void sample_kernel(
    const u16* __restrict__ vol, const float* __restrict__ offb,
    const float* __restrict__ lgb, u16* __restrict__ outp)
{
    int wid = threadIdx.x >> 6, lane = threadIdx.x & 63;
    int bx = blockIdx.x;                               // 4000 = 8 slabs x 500
    int bn = ((bx & 7) * 500 + (bx >> 3)) * 4 + wid;   // token 0..15999
    int h = lane >> 3, cl = lane & 7;
    int b = bn / NTOK, n = bn - b * NTOK;
    int y = n / 400;
    int r2 = n - y * 400;
    int x = r2 / 20;
    int z = r2 - x * 20;

    const float* op = offb + (size_t)bn * 96 + h * 12;
    const float* lp = lgb + (size_t)bn * 32 + h * 4;
    float l0 = lp[0], l1 = lp[1], l2 = lp[2], l3 = lp[3];
    float mx = fmaxf(fmaxf(l0, l1), fmaxf(l2, l3));
    float e0 = expf(l0 - mx), e1 = expf(l1 - mx), e2 = expf(l2 - mx), e3 = expf(l3 - mx);
    float inv = 1.f / (e0 + e1 + e2 + e3);
    float at[4] = {e0 * inv, e1 * inv, e2 * inv, e3 * inv};

    const u16* volb = vol + b * (NTOK * C_DIM) + h * HDIM + cl * 8;
    float acc[8] = {};
#pragma unroll 1
    for (int p = 0; p < 4; p++) {
        float o0 = fminf(fmaxf(op[p * 3 + 0], -3.f), 3.f);
        float o1 = fminf(fmaxf(op[p * 3 + 1], -3.f), 3.f);
        float o2 = fminf(fmaxf(op[p * 3 + 2], -3.f), 3.f);
        float ix = fminf(fmaxf((float)y + o0, 0.f), 19.f);  // W axis
        float iy = fminf(fmaxf((float)x + o1, 0.f), 19.f);  // H axis
        float iz = fminf(fmaxf((float)z + o2, 0.f), 19.f);  // D axis
        float xf = floorf(ix), yf = floorf(iy), zf = floorf(iz);
        float fx = ix - xf, fy = iy - yf, fz = iz - zf;
        int x0 = (int)xf, y0 = (int)yf, z0 = (int)zf;
        int x1 = imin(x0 + 1, 19), y1 = imin(y0 + 1, 19), z1 = imin(z0 + 1, 19);
        // spatial = yi*400 + xi*20 + zi, channels contiguous (stride C_DIM)
        int s00 = y0 * 400 + x0 * 20, s01 = y0 * 400 + x1 * 20;
        int s10 = y1 * 400 + x0 * 20, s11 = y1 * 400 + x1 * 20;
        uint4 v000 = *(const uint4*)(volb + (s00 + z0) * C_DIM);
        uint4 v001 = *(const uint4*)(volb + (s01 + z0) * C_DIM);
        uint4 v010 = *(const uint4*)(volb + (s10 + z0) * C_DIM);
        uint4 v011 = *(const uint4*)(volb + (s11 + z0) * C_DIM);
        uint4 v100 = *(const uint4*)(volb + (s00 + z1) * C_DIM);
        uint4 v101 = *(const uint4*)(volb + (s01 + z1) * C_DIM);
        uint4 v110 = *(const uint4*)(volb + (s10 + z1) * C_DIM);
        uint4 v111 = *(const uint4*)(volb + (s11 + z1) * C_DIM);
        float wz0 = (1.f - fz) * at[p], wz1 = fz * at[p];
        float w00 = wz0 * (1.f - fy), w01 = wz0 * fy;
        float w10 = wz1 * (1.f - fy), w11 = wz1 * fy;
        float gx0 = 1.f - fx;
        fmah(acc, v000, w00 * gx0); fmah(acc, v001, w00 * fx);
        fmah(acc, v010, w01 * gx0); fmah(acc, v011, w01 * fx);
        fmah(acc, v100, w10 * gx0); fmah(acc, v101, w10 * fx);
        fmah(acc, v110, w11 * gx0); fmah(acc, v111, w11 * fx);
    }
    u16 ov[8];
#pragma unroll
    for (int c = 0; c < 8; c++) ov[c] = f2bf(acc[c]);
    *reinterpret_cast<uint4*>(outp + (size_t)bn * C_DIM + h * HDIM + cl * 8) =
        *reinterpret_cast<uint4*>(ov);
}

// ---------------------------------------------------------------------------
// Launch
// ---------------------------------------------------------------------------
extern "C" void kernel_launch(void* const* d_in, const int* in_sizes, int n_in,
                              void* d_out, int out_size, void* d_ws, size_t ws_size,
                              hipStream_t stream)
{
    const float* f_query = (const float*)d_in[0];
    const float* f_kv    = (const float*)d_in[1];
    const float* ln_g    = (const float*)d_in[2];
    const float* ln_b    = (const float*)d_in[3];
    const float* Wq      = (const float*)d_in[4];
    const float* bq      = (const float*)d_in[5];
    const float* Wo1     = (const float*)d_in[6];
    const float* bo1     = (const float*)d_in[7];
    const float* Wo2     = (const float*)d_in[8];
    const float* bo2     = (const float*)d_in[9];
    const float* Wa      = (const float*)d_in[10];
    const float* ba      = (const float*)d_in[11];
    const float* Wout    = (const float*)d_in[12];
    const float* bout    = (const float*)d_in[13];
    float* out = (float*)d_out;

    float* ws = (float*)d_ws;
    float* offb = ws;                     // 1,536,000 f
    float* lgb  = ws + 1536000;           //   512,000 f
    u16* kvT   = (u16*)(ws + 2048000);    // 8,192,000 u16 (f16 channels-last)
    u16* qb    = (u16*)(ws + 6144000);    // 8,192,000 u16 (q; later sampled)
    u16* Qb    = (u16*)(ws + 10240000);   // 8,192,000 u16
    u16* hid   = (u16*)(ws + 14336000);   // 8,192,000 u16
    u16* WqT   = (u16*)(ws + 18432000);   // 512x512
    u16* Wo1T  = WqT + 262144;
    u16* WoutT = Wo1T + 262144;
    u16* Wo2T  = WoutT + 262144;          // 128x512 (96 valid, pad 0)
    u16* WaT   = Wo2T + 65536;            // 128x512 (32 valid, pad 0)
    // total ~75.6 MiB

    dim3 blk(256);
    // all weight transpose-converts in one dispatch
    wcvt_all<<<dim3(16, 16, 5), blk, 0, stream>>>(
        Wq, WqT, Wo1, Wo1T, Wout, WoutT, Wo2, Wo2T, Wa, WaT);
    // f_kv (B,C,N) fp32 -> kvT (B,N,C) f16
    transpose_c2l_f16<<<dim3(250, 16, 2), blk, 0, stream>>>(f_kv, kvT);
    // q = LN(transpose(f_query)) -> bf16, fused LDS tile
    ln_fused<<<dim3(500), blk, 0, stream>>>(f_query, ln_g, ln_b, qb);
    // Q = q @ Wq + bq -> bf16
    gemm_bf16<<<dim3(4, 125), blk, 0, stream>>>(qb, WqT, bq, nullptr, Qb, 512, 512, 0, 1);
    // hidden = relu(Q @ Wo1 + bo1) -> bf16
    gemm_bf16<<<dim3(4, 125), blk, 0, stream>>>(Qb, Wo1T, bo1, nullptr, hid, 512, 512, 1, 1);
    // off = hidden @ Wo2 + bo2 (fp32) AND logits = Q @ Wa + ba (fp32), one dispatch
    gemm_dual<<<dim3(1, 125, 2), blk, 0, stream>>>(
        hid, Wo2T, bo2, offb, 96, Qb, WaT, ba, lgb, 32);
    // fused sample/softmax/einsum -> qb (bf16)
    sample_kernel<<<dim3(4000), blk, 0, stream>>>(kvT, offb, lgb, qb);
    // out(B,C,N) = (sampled @ Wout + bout)^T  via  WoutT @ sampled^T, mode 2
    gemm_bf16<<<dim3(125, 4), blk, 0, stream>>>(WoutT, qb, bout, out, nullptr, 16000, 0, 0, 2);
}